// Round 10
// baseline (409.719 us; speedup 1.0000x reference)
//
#include <hip/hip_runtime.h>
#include <hip/hip_bf16.h>

typedef int i32x4 __attribute__((ext_vector_type(4)));

#define N_TOKENS 32768
#define N_CODES 4096
#define DIM 1280
#define NT 20            // K-tiles of 64 (i8)

__device__ __forceinline__ void load_lds16(const void* g, void* l) {
    __builtin_amdgcn_global_load_lds(
        (const __attribute__((address_space(1))) unsigned int*)g,
        (__attribute__((address_space(3))) unsigned int*)l,
        16, 0, 0);
}

// ---------------------------------------------------------------------------
// Kernel 0: per-row symmetric int8 quantize (RNE), verified r5-r9.
// FRAG=false: row-major (E). FRAG=true: fragment-major (X, r7-verified):
// byte for (row, k) at ((row>>8)*20 + (k>>6))*16384 + ((row>>4)&15)*1024 +
// (row&15)*64 + (k&63) -> a wave's 16x64 A-fragment is one contiguous 1024B
// block (lane offset lr*64 + g*16).
// ---------------------------------------------------------------------------
template <bool FRAG>
__global__ __launch_bounds__(256) void quantize_i8_kernel(
    const float* __restrict__ src, signed char* __restrict__ dst,
    float* __restrict__ scale, int nrows)
{
    int row = blockIdx.x * 4 + (threadIdx.x >> 6);
    if (row >= nrows) return;
    int lane = threadIdx.x & 63;
    const float4* s4 = (const float4*)(src + (size_t)row * DIM);
    float4 v[5];
    float amax = 0.f;
    #pragma unroll
    for (int j = 0; j < 5; ++j) {
        v[j] = s4[j * 64 + lane];
        amax = fmaxf(amax, fmaxf(fmaxf(fabsf(v[j].x), fabsf(v[j].y)),
                                 fmaxf(fabsf(v[j].z), fabsf(v[j].w))));
    }
    #pragma unroll
    for (int d = 1; d < 64; d <<= 1) amax = fmaxf(amax, __shfl_xor(amax, d));
    amax = fmaxf(amax, 1e-20f);
    float inv = 127.0f / amax;
    #pragma unroll
    for (int j = 0; j < 5; ++j) {
        int q0 = (int)rintf(v[j].x * inv), q1 = (int)rintf(v[j].y * inv);
        int q2 = (int)rintf(v[j].z * inv), q3 = (int)rintf(v[j].w * inv);
        int w = (q0 & 0xFF) | ((q1 & 0xFF) << 8) |
                ((q2 & 0xFF) << 16) | ((q3 & 0xFF) << 24);
        if (FRAG) {
            int c = (j * 64 + lane) << 2;            // byte col 0..1279
            size_t dest = ((size_t)((row >> 8) * 20 + (c >> 6)) << 14)
                        + (((row >> 4) & 15) << 10) + ((row & 15) << 6) + (c & 63);
            *(int*)(dst + dest) = w;
        } else {
            ((int*)(dst + (size_t)row * DIM))[j * 64 + lane] = w;
        }
    }
    if (lane == 0) scale[row] = amax * (1.0f / 127.0f);
}

// ---------------------------------------------------------------------------
// Kernel 1: i8 GEMM 256x256, 16 waves (4x4 grid, wave tile 64x64), BK=64.
// A: direct global->reg from fragment-major XqF, REGISTER PING-PONG aA/aB
// with FULL-ITERATION prefetch lead (the r7 failure was 1-barrier lead).
// B: LDS-staged, 4 x 16KB buffers, r6-verified swizzle, 1 gl_lds/thread/iter.
//
// VMEM LEDGER (per thread, exactly 5 issues/iter: 1 B gl_lds + 4 A loads):
//   prologue: STAGE_B(0), STAGE_B(1), LOAD_A(0)->aA   [6 pending]
//             vmcnt(5) retires B(0); barrier.
//   iter t:   READ_B(t) [ds];  STAGE_B(t+2);  LOAD_A(t+1)->other
//             [pending: B(t+1), A(t)x4, B(t+2), A(t+1)x4 = 10]
//             vmcnt(5) -> retires B(t+1) (for next iter's ds_read after
//             barrier) AND A(t) (for this iter's MFMA); s_barrier makes all
//             waves' B(t+1) gl_lds globally visible; MFMA(t).
//   B overwrite: buf[t&3] rewritten by STAGE_B at iter t+2; reader's
//             ds_read data consumed by MFMA(t) before iter t+1's end
//             barrier < writer's iter t+2 issue => 2-barrier distance, safe.
//   tail:     t=18 issues only LOAD_A(19): vmcnt(4) retires B(19)+A(18);
//             t=19 issues nothing: vmcnt(0) retires A(19).
// Register budget: aA 16 + aB 16 + b 16 + acc 64 + addr ~12 <= 128 =>
// 4 waves/SIMD (launch_bounds(1024,4)). sched_barrier(0) after each MFMA
// cluster stops ds_read hoisting (would rename b, +16 regs).
// LDS read traffic halves vs r6 (B only): ~770 cyc/CU/iter vs matrix 1306
// => matrix-bound. A re-read 4x served by L1 (same 1KB blocks read by the
// 4 wn-waves within one barrier-locked iter).
// ---------------------------------------------------------------------------
__global__ __launch_bounds__(1024, 4) void gemm_argmax_kernel(
    const signed char* __restrict__ XqF, const signed char* __restrict__ Eq,
    const float* __restrict__ sx, const float* __restrict__ se,
    unsigned* __restrict__ pkeys)
{
    __shared__ __align__(16) char lds[4 * 16384];   // 64 KB (B only)

    int bid = blockIdx.x;
    // bijective XCD swizzle; each XCD owns 2 cb0 values x all 128 rb
    int swz = (bid & 7) * 256 + (bid >> 3);
    int cb0 = swz >> 7, rb = swz & 127;
    int row0 = rb << 8, col0 = cb0 << 8;

    int tid = threadIdx.x;
    int wid = tid >> 6, lane = tid & 63;
    int wm = wid >> 2, wn = wid & 3;          // 4x4 wave grid, tile 64x64
    int lr = lane & 15, g = lane >> 4;

    // B fragment read offset (r6-verified swizzle)
    int slot = (((lr & 1) << 2) + g) ^ ((lr >> 1) & 7);
    int boff = ((wn << 5) + (lr >> 1)) * 128 + slot * 16;

    // B staging constants (r6-verified): 1024 slots, 1 per thread
    int rp = tid >> 3, c = tid & 7;
    int cp = c ^ (rp & 7);
    int gr = (rp << 1) + (cp >> 2);
    const signed char* srcB = Eq + (size_t)(col0 + gr) * DIM + ((cp & 3) << 4);

    // A fragment-major base (r7-verified layout): + t*16384 + m*1024
    const signed char* Aptr = XqF + (size_t)rb * (NT * 16384)
                              + (wm << 12) + (lr << 6) + (g << 4);

    i32x4 acc[4][4] = {};
    i32x4 aA[4], aB[4], b[4];

    auto STAGE_B = [&](int t) {
        load_lds16(srcB + (t << 6), lds + ((t & 3) << 14) + (tid << 4));
    };
    auto LOAD_A = [&](int t, i32x4* a) {
        const signed char* p = Aptr + (t << 14);
        #pragma unroll
        for (int m = 0; m < 4; ++m) a[m] = *(const i32x4*)(p + (m << 10));
    };
    auto READ_B = [&](int t) {
        const char* pB = lds + ((t & 3) << 14) + boff;
        #pragma unroll
        for (int n = 0; n < 4; ++n) b[n] = *(const i32x4*)(pB + (n << 10));
    };
    auto MFMA16 = [&](i32x4* a) {
        __builtin_amdgcn_s_setprio(1);
        #pragma unroll
        for (int m = 0; m < 4; ++m)
            #pragma unroll
            for (int n = 0; n < 4; ++n)
                acc[m][n] = __builtin_amdgcn_mfma_i32_16x16x64_i8(
                    a[m], b[n], acc[m][n], 0, 0, 0);
        __builtin_amdgcn_s_setprio(0);
        __builtin_amdgcn_sched_barrier(0);
    };

    STAGE_B(0); STAGE_B(1); LOAD_A(0, aA);
    asm volatile("s_waitcnt vmcnt(5)" ::: "memory");
    __builtin_amdgcn_s_barrier();
    __builtin_amdgcn_sched_barrier(0);

    #pragma unroll 1
    for (int p = 0; p < 9; ++p) {       // t = 2p, 2p+1  (0..17)
        int t = p * 2;
        READ_B(t);
        STAGE_B(t + 2);
        LOAD_A(t + 1, aB);
        asm volatile("s_waitcnt vmcnt(5)" ::: "memory");
        __builtin_amdgcn_s_barrier();
        __builtin_amdgcn_sched_barrier(0);
        MFMA16(aA);
        READ_B(t + 1);
        STAGE_B(t + 3);
        LOAD_A(t + 2, aA);
        asm volatile("s_waitcnt vmcnt(5)" ::: "memory");
        __builtin_amdgcn_s_barrier();
        __builtin_amdgcn_sched_barrier(0);
        MFMA16(aB);
    }
    // t = 18
    READ_B(18);
    LOAD_A(19, aB);
    asm volatile("s_waitcnt vmcnt(4)" ::: "memory");
    __builtin_amdgcn_s_barrier();
    __builtin_amdgcn_sched_barrier(0);
    MFMA16(aA);
    // t = 19 (B(19) already globally visible via t=18's vmcnt(4)+barrier)
    READ_B(19);
    asm volatile("s_waitcnt vmcnt(0)" ::: "memory");
    __builtin_amdgcn_sched_barrier(0);
    MFMA16(aB);
    __syncthreads();   // drain; LDS reused for epilogue merge

    // ---- dequant + fused top-2 argmax epilogue (r6-verified) ----
    // C/D frag layout (dtype-independent): col = lr, row = g*4 + r.
    float se_l[4];
    #pragma unroll
    for (int n = 0; n < 4; ++n)
        se_l[n] = se[col0 + (wn << 6) + (n << 4) + lr];

    uint2* lk2 = (uint2*)lds;   // [256 rows][4 wn]
    #pragma unroll
    for (int m = 0; m < 4; ++m) {
        #pragma unroll
        for (int r = 0; r < 4; ++r) {
            int row = (wm << 6) + (m << 4) + (g << 2) + r;
            float fx = sx[row0 + row];
            unsigned b1 = 0, b2 = 0;
            #pragma unroll
            for (int n = 0; n < 4; ++n) {
                float s = (float)acc[m][n][r] * (fx * se_l[n]);
                int cib = ((wn & 1) << 6) + (n << 4) + lr;   // col in 128-block
                unsigned u = __float_as_uint(s);
                u = (u & 0x80000000u) ? ~u : (u | 0x80000000u);
                unsigned key = (u & 0xFFFFFF80u) | (unsigned)(127 - cib);
                if (key > b1) { b2 = b1; b1 = key; }
                else if (key > b2) b2 = key;
            }
            #pragma unroll
            for (int d = 1; d < 16; d <<= 1) {   // merge across 16 lanes (lr)
                unsigned o1 = __shfl_xor(b1, d), o2 = __shfl_xor(b2, d);
                if (o1 > b1) { b2 = (b1 > o2) ? b1 : o2; b1 = o1; }
                else if (o1 > b2) b2 = o1;
            }
            if (lr == 0) {
                uint2 v; v.x = b1; v.y = b2;
                lk2[(row << 2) + wn] = v;
            }
        }
    }
    __syncthreads();
    if (tid < 512) {
        // wn {0,1} -> 128-col-block h=0; wn {2,3} -> h=1
        int row = tid >> 1, h = tid & 1;
        uint2 p0 = lk2[(row << 2) + (h << 1)];
        uint2 p1 = lk2[(row << 2) + (h << 1) + 1];
        unsigned b1 = p0.x, b2 = p0.y;
        if (p1.x > b1) { b2 = (b1 > p1.y) ? b1 : p1.y; b1 = p1.x; }
        else if (p1.x > b2) b2 = p1.x;
        uint2 out; out.x = b1; out.y = b2;
        *(uint2*)&pkeys[((size_t)(row0 + row) << 6) + (((cb0 << 1) + h) << 1)] = out;
    }
}

// ---------------------------------------------------------------------------
// Kernel 2: fused exact fp64 refine + gather + loss partial. One wave/token.
// Threshold 3e-3 (~9 sigma i8 noise). Verified r5-r9.
// ---------------------------------------------------------------------------
__global__ __launch_bounds__(64) void refine_gather_kernel(
    const float* __restrict__ X, const float* __restrict__ E,
    const unsigned* __restrict__ pkeys, float* __restrict__ outq,
    float* __restrict__ outidx, float* __restrict__ sums)
{
    int token = blockIdx.x;
    int lane = threadIdx.x;
    unsigned k = pkeys[((size_t)token << 6) + lane];
    unsigned m = k & 0xFFFFFF80u;
    float s = __uint_as_float((m & 0x80000000u) ? (m & 0x7FFFFFFFu) : ~m);
    float smax = s;
    #pragma unroll
    for (int d = 1; d < 64; d <<= 1) smax = fmaxf(smax, __shfl_xor(smax, d));
    bool cand = s >= smax - 3e-3f;
    unsigned long long ball = __ballot(cand);

    const float4* x4 = (const float4*)(X + (size_t)token * DIM);
    float4 xv[5];
    #pragma unroll
    for (int j = 0; j < 5; ++j) xv[j] = x4[j * 64 + lane];

    double best_s = -1.0e300;
    int best_i = 0x7FFFFFFF;
    while (ball) {
        int src = __ffsll(ball) - 1;
        ball &= ball - 1;
        unsigned ck = __shfl(k, src);
        int cidx = ((src >> 1) << 7) + (127 - (int)(ck & 127u));
        const float4* e4 = (const float4*)(E + (size_t)cidx * DIM);
        double d = 0.0, ee = 0.0;
        #pragma unroll
        for (int j = 0; j < 5; ++j) {
            float4 ev = e4[j * 64 + lane];
            d += (double)xv[j].x * (double)ev.x + (double)xv[j].y * (double)ev.y
               + (double)xv[j].z * (double)ev.z + (double)xv[j].w * (double)ev.w;
            ee += (double)ev.x * (double)ev.x + (double)ev.y * (double)ev.y
                + (double)ev.z * (double)ev.z + (double)ev.w * (double)ev.w;
        }
        #pragma unroll
        for (int dd = 1; dd < 64; dd <<= 1) {
            d += __shfl_xor(d, dd);
            ee += __shfl_xor(ee, dd);
        }
        double sc = 2.0 * d - ee;
        if (sc > best_s || (sc == best_s && cidx < best_i)) { best_s = sc; best_i = cidx; }
    }

    const float4* e4 = (const float4*)(E + (size_t)best_i * DIM);
    float4* o4 = (float4*)(outq + (size_t)token * DIM);
    float local = 0.0f;
    #pragma unroll
    for (int j = 0; j < 5; ++j) {
        float4 q = e4[j * 64 + lane];
        o4[j * 64 + lane] = q;
        float dx = xv[j].x - q.x, dy = xv[j].y - q.y;
        float dz = xv[j].z - q.z, dw = xv[j].w - q.w;
        local += dx * dx + dy * dy + dz * dz + dw * dw;
    }
    #pragma unroll
    for (int d = 1; d < 64; d <<= 1) local += __shfl_xor(local, d);
    if (lane == 0) {
        sums[token] = local;
        outidx[token] = (float)best_i;
    }
}

// ---------------------------------------------------------------------------
// Kernel 3: deterministic final loss reduction (fixed tree).
// ---------------------------------------------------------------------------
__global__ __launch_bounds__(256) void loss_kernel(
    const float* __restrict__ sums, float* __restrict__ out_loss)
{
    __shared__ double red[256];
    int t = threadIdx.x;
    double s = 0.0;
    for (int i = t; i < N_TOKENS; i += 256) s += (double)sums[i];
    red[t] = s;
    __syncthreads();
    for (int off = 128; off > 0; off >>= 1) {
        if (t < off) red[t] += red[t + off];
        __syncthreads();
    }
    if (t == 0) out_loss[0] = (float)(red[0] / (double)((size_t)N_TOKENS * DIM));
}

extern "C" void kernel_launch(void* const* d_in, const int* in_sizes, int n_in,
                              void* d_out, int out_size, void* d_ws, size_t ws_size,
                              hipStream_t stream)
{
    const float* X = (const float*)d_in[0];   // (32768, 1280) fp32
    const float* E = (const float*)d_in[1];   // (4096, 1280) fp32

    float* outq = (float*)d_out;                       // (32768,1280)
    float* outidx = outq + (size_t)N_TOKENS * DIM;     // (32768,) as float
    float* outloss = outidx + N_TOKENS;                // scalar

    // i8 temps + scales inside outq region (47.3 MB of 167.9 MB); consumed
    // by GEMM, then fully overwritten by refine_gather in-stream.
    signed char* XqF = (signed char*)d_out;                       // 41.9 MB frag-major
    signed char* Eq = XqF + (size_t)N_TOKENS * DIM;               // 5.2 MB row-major
    float* sxs = (float*)(Eq + (size_t)N_CODES * DIM);            // 128 KB
    float* ses = sxs + N_TOKENS;                                  // 16 KB

    unsigned* pkeys = (unsigned*)d_ws;                            // 8 MB
    float* sums = (float*)((char*)d_ws + (size_t)N_TOKENS * 64 * sizeof(unsigned));

    quantize_i8_kernel<true><<<dim3(N_TOKENS / 4), dim3(256), 0, stream>>>(X, XqF, sxs, N_TOKENS);
    quantize_i8_kernel<false><<<dim3(N_CODES / 4), dim3(256), 0, stream>>>(E, Eq, ses, N_CODES);
    gemm_argmax_kernel<<<dim3(2048), dim3(1024), 0, stream>>>(XqF, Eq, sxs, ses, pkeys);
    refine_gather_kernel<<<dim3(N_TOKENS), dim3(64), 0, stream>>>(X, E, pkeys, outq, outidx, sums);
    loss_kernel<<<dim3(1), dim3(256), 0, stream>>>(sums, outloss);
}

// Round 11
// 391.853 us; speedup vs baseline: 1.0456x; 1.0456x over previous
//
#include <hip/hip_runtime.h>
#include <hip/hip_bf16.h>

typedef int i32x4 __attribute__((ext_vector_type(4)));

#define N_TOKENS 32768
#define N_CODES 4096
#define DIM 1280
#define NT 20            // K-tiles of 64 (i8)
#define BUFSZ 32768      // A 16KB + B 16KB per K-tile buffer

__device__ __forceinline__ void load_lds16(const void* g, void* l) {
    __builtin_amdgcn_global_load_lds(
        (const __attribute__((address_space(1))) unsigned int*)g,
        (__attribute__((address_space(3))) unsigned int*)l,
        16, 0, 0);
}

// ---------------------------------------------------------------------------
// Kernel 0: per-row symmetric int8 quantize (RNE), X and E fused in one
// launch. Verified r5-r10: exact-int dot => score err sigma ~3.4e-4,
// zero-mean; refine threshold 3e-3 ~ 9 sigma.
// ---------------------------------------------------------------------------
__global__ __launch_bounds__(256) void quantize_i8_kernel(
    const float* __restrict__ X, const float* __restrict__ E,
    signed char* __restrict__ Xq, signed char* __restrict__ Eq,
    float* __restrict__ sxs, float* __restrict__ ses)
{
    int row = blockIdx.x * 4 + (threadIdx.x >> 6);
    const float* src;
    signed char* dst;
    float* scale;
    if (row < N_TOKENS) {
        src = X + (size_t)row * DIM; dst = Xq + (size_t)row * DIM; scale = sxs + row;
    } else {
        int r = row - N_TOKENS;
        if (r >= N_CODES) return;
        src = E + (size_t)r * DIM; dst = Eq + (size_t)r * DIM; scale = ses + r;
    }
    int lane = threadIdx.x & 63;
    const float4* s4 = (const float4*)src;
    float4 v[5];
    float amax = 0.f;
    #pragma unroll
    for (int j = 0; j < 5; ++j) {
        v[j] = s4[j * 64 + lane];
        amax = fmaxf(amax, fmaxf(fmaxf(fabsf(v[j].x), fabsf(v[j].y)),
                                 fmaxf(fabsf(v[j].z), fabsf(v[j].w))));
    }
    #pragma unroll
    for (int d = 1; d < 64; d <<= 1) amax = fmaxf(amax, __shfl_xor(amax, d));
    amax = fmaxf(amax, 1e-20f);
    float inv = 127.0f / amax;
    int* d4 = (int*)dst;
    #pragma unroll
    for (int j = 0; j < 5; ++j) {
        int q0 = (int)rintf(v[j].x * inv), q1 = (int)rintf(v[j].y * inv);
        int q2 = (int)rintf(v[j].z * inv), q3 = (int)rintf(v[j].w * inv);
        d4[j * 64 + lane] = (q0 & 0xFF) | ((q1 & 0xFF) << 8) |
                            ((q2 & 0xFF) << 16) | ((q3 & 0xFF) << 24);
    }
    if (lane == 0) *scale = amax * (1.0f / 127.0f);
}

// ---------------------------------------------------------------------------
// Kernel 1: i8 GEMM 256x256, 16 waves (4x4, wave tile 64x64), BK=64,
// mfma_i32_16x16x64_i8 — r6 champion core with 2-TILE SPANS.
//
// SPAN LEDGER (2 loads/thread/STAGE, 4 buffers):
//   prologue: STAGE(0..3) [8 pending]; vmcnt(4) retires S0,S1 (tiles 0,1
//             certified); barrier.
//   span s (tiles t=2s, 2s+1):   [invariant at entry: pending = S(t+2),
//             S(t+3) = 4 loads; tiles t, t+1 certified by span s-1]
//     COMPUTE(t); COMPUTE(t+1)   (no barrier between: both certified; the
//             compiler may interleave t+1 ds_reads under t MFMAs)
//     barrier  -> every wave's MFMAs done => every ds_read of bufs
//             [t&3],[(t+1)&3] COMPLETE (MFMA consumed the data)
//     STAGE(t+4) -> buf[t&3]; STAGE(t+5) -> buf[(t+1)&3]  (just-read bufs;
//             same safety class as r9/m201's stage-into-read-buffer)
//     vmcnt(4) retires S(t+2),S(t+3) => tiles for span s+1 certified
//     barrier; sched_barrier.
//   tail: span 8 (tiles 16,17): no stage; vmcnt(0) retires S18,S19; barrier.
//         span 9 (tiles 18,19): no stage/vmcnt.
// Buffer overwrite distance and certification identical in strength to r6.
// XCD swizzle: cb0-ADJACENT (rb=i>>1, cb0=2*xcd+(i&1)) so the 2 blocks
// sharing an A-panel are launch-adjacent => A-panel L2 reuse (FETCH drop).
// ---------------------------------------------------------------------------
__global__ __launch_bounds__(1024, 4) void gemm_argmax_kernel(
    const signed char* __restrict__ Xq, const signed char* __restrict__ Eq,
    const float* __restrict__ sx, const float* __restrict__ se,
    unsigned* __restrict__ pkeys)
{
    __shared__ __align__(16) char lds[4 * BUFSZ];   // 128 KB

    int bid = blockIdx.x;
    int xcd = bid & 7, i = bid >> 3;          // i in 0..255 per XCD
    int cb0 = (xcd << 1) + (i & 1);           // 0..15, adjacent pair shares rb
    int rb = i >> 1;                          // 0..127
    int row0 = rb << 8, col0 = cb0 << 8;

    int tid = threadIdx.x;
    int wid = tid >> 6, lane = tid & 63;
    int wm = wid >> 2, wn = wid & 3;          // 4x4 wave grid, tile 64x64
    int lr = lane & 15, g = lane >> 4;

    // per-lane swizzled fragment offsets (r6-verified; row bases multiples
    // of 16 => rp&7 == (lr>>1)&7)
    int slot = (((lr & 1) << 2) + g) ^ ((lr >> 1) & 7);
    int aoff = ((wm << 5) + (lr >> 1)) * 128 + slot * 16;            // A region
    int boff = 16384 + ((wn << 5) + (lr >> 1)) * 128 + slot * 16;    // B region

    i32x4 acc[4][4] = {};

    auto STAGE = [&](int t) {
        int base = (t & 3) * BUFSZ;
        int k0 = t << 6;                     // byte k-offset (i8)
        int f = tid;                         // slot 0..1023
        int rp = f >> 3, c = f & 7;
        int cp = c ^ (rp & 7);               // pre-swizzled source chunk
        int gr = (rp << 1) + (cp >> 2);      // global row in tile
        int kc = k0 + ((cp & 3) << 4);       // 16B k-chunk
        load_lds16(Xq + (size_t)(row0 + gr) * DIM + kc, lds + base + (f << 4));
        load_lds16(Eq + (size_t)(col0 + gr) * DIM + kc, lds + base + 16384 + (f << 4));
    };

    auto COMPUTE = [&](int t) {
        int base = (t & 3) * BUFSZ;
        const char* pA = lds + base + aoff;
        const char* pB = lds + base + boff;
        i32x4 a[4], b[4];
        #pragma unroll
        for (int m = 0; m < 4; ++m) a[m] = *(const i32x4*)(pA + (m << 10));
        #pragma unroll
        for (int n = 0; n < 4; ++n) b[n] = *(const i32x4*)(pB + (n << 10));
        __builtin_amdgcn_s_setprio(1);
        #pragma unroll
        for (int m = 0; m < 4; ++m)
            #pragma unroll
            for (int n = 0; n < 4; ++n)
                acc[m][n] = __builtin_amdgcn_mfma_i32_16x16x64_i8(
                    a[m], b[n], acc[m][n], 0, 0, 0);
        __builtin_amdgcn_s_setprio(0);
    };

    STAGE(0); STAGE(1); STAGE(2); STAGE(3);       // 8 outstanding
    asm volatile("s_waitcnt vmcnt(4)" ::: "memory");
    __builtin_amdgcn_s_barrier();
    __builtin_amdgcn_sched_barrier(0);

    #pragma unroll 1
    for (int s = 0; s < 8; ++s) {
        int t = s * 2;
        COMPUTE(t);
        COMPUTE(t + 1);
        __builtin_amdgcn_s_barrier();        // all reads of t,t+1 complete
        __builtin_amdgcn_sched_barrier(0);
        STAGE(t + 4);
        STAGE(t + 5);
        asm volatile("s_waitcnt vmcnt(4)" ::: "memory");  // certify t+2,t+3
        __builtin_amdgcn_s_barrier();
        __builtin_amdgcn_sched_barrier(0);
    }
    COMPUTE(16);
    COMPUTE(17);
    asm volatile("s_waitcnt vmcnt(0)" ::: "memory");      // certify 18,19
    __builtin_amdgcn_s_barrier();
    __builtin_amdgcn_sched_barrier(0);
    COMPUTE(18);
    COMPUTE(19);
    __syncthreads();   // drain; LDS reused for epilogue merge

    // ---- dequant + fused top-2 argmax epilogue (r6-verified) ----
    // C/D frag layout (dtype-independent): col = lr, row = g*4 + r.
    float se_l[4];
    #pragma unroll
    for (int n = 0; n < 4; ++n)
        se_l[n] = se[col0 + (wn << 6) + (n << 4) + lr];

    uint2* lk2 = (uint2*)lds;   // [256 rows][4 wn]
    #pragma unroll
    for (int m = 0; m < 4; ++m) {
        #pragma unroll
        for (int r = 0; r < 4; ++r) {
            int row = (wm << 6) + (m << 4) + (g << 2) + r;
            float fx = sx[row0 + row];
            unsigned b1 = 0, b2 = 0;
            #pragma unroll
            for (int n = 0; n < 4; ++n) {
                float s = (float)acc[m][n][r] * (fx * se_l[n]);
                int cib = ((wn & 1) << 6) + (n << 4) + lr;   // col in 128-block
                unsigned u = __float_as_uint(s);
                u = (u & 0x80000000u) ? ~u : (u | 0x80000000u);
                unsigned key = (u & 0xFFFFFF80u) | (unsigned)(127 - cib);
                if (key > b1) { b2 = b1; b1 = key; }
                else if (key > b2) b2 = key;
            }
            #pragma unroll
            for (int d = 1; d < 16; d <<= 1) {   // merge across 16 lanes (lr)
                unsigned o1 = __shfl_xor(b1, d), o2 = __shfl_xor(b2, d);
                if (o1 > b1) { b2 = (b1 > o2) ? b1 : o2; b1 = o1; }
                else if (o1 > b2) b2 = o1;
            }
            if (lr == 0) {
                uint2 v; v.x = b1; v.y = b2;
                lk2[(row << 2) + wn] = v;
            }
        }
    }
    __syncthreads();
    if (tid < 512) {
        // wn {0,1} -> 128-col-block h=0; wn {2,3} -> h=1
        int row = tid >> 1, h = tid & 1;
        uint2 p0 = lk2[(row << 2) + (h << 1)];
        uint2 p1 = lk2[(row << 2) + (h << 1) + 1];
        unsigned b1 = p0.x, b2 = p0.y;
        if (p1.x > b1) { b2 = (b1 > p1.y) ? b1 : p1.y; b1 = p1.x; }
        else if (p1.x > b2) b2 = p1.x;
        uint2 out; out.x = b1; out.y = b2;
        *(uint2*)&pkeys[((size_t)(row0 + row) << 6) + (((cb0 << 1) + h) << 1)] = out;
    }
}

// ---------------------------------------------------------------------------
// Kernel 2: fused exact fp64 refine + gather + loss partial. One wave/token.
// Threshold 3e-3 (~9 sigma i8 noise). FAST PATH: if exactly one candidate
// is within threshold of the max, it is provably the true argmax (noise
// bound) -> skip the fp64 rescore loop entirely (~65% of tokens).
// ---------------------------------------------------------------------------
__global__ __launch_bounds__(64) void refine_gather_kernel(
    const float* __restrict__ X, const float* __restrict__ E,
    const unsigned* __restrict__ pkeys, float* __restrict__ outq,
    float* __restrict__ outidx, float* __restrict__ sums)
{
    int token = blockIdx.x;
    int lane = threadIdx.x;
    unsigned k = pkeys[((size_t)token << 6) + lane];
    unsigned m = k & 0xFFFFFF80u;
    float s = __uint_as_float((m & 0x80000000u) ? (m & 0x7FFFFFFFu) : ~m);
    float smax = s;
    #pragma unroll
    for (int d = 1; d < 64; d <<= 1) smax = fmaxf(smax, __shfl_xor(smax, d));
    bool cand = s >= smax - 3e-3f;
    unsigned long long ball = __ballot(cand);

    const float4* x4 = (const float4*)(X + (size_t)token * DIM);
    float4 xv[5];
    #pragma unroll
    for (int j = 0; j < 5; ++j) xv[j] = x4[j * 64 + lane];

    int best_i;
    if (__popcll(ball) == 1) {
        int src = __ffsll(ball) - 1;
        unsigned ck = __shfl(k, src);
        best_i = ((src >> 1) << 7) + (127 - (int)(ck & 127u));
    } else {
        double best_s = -1.0e300;
        best_i = 0x7FFFFFFF;
        while (ball) {
            int src = __ffsll(ball) - 1;
            ball &= ball - 1;
            unsigned ck = __shfl(k, src);
            int cidx = ((src >> 1) << 7) + (127 - (int)(ck & 127u));
            const float4* e4 = (const float4*)(E + (size_t)cidx * DIM);
            double d = 0.0, ee = 0.0;
            #pragma unroll
            for (int j = 0; j < 5; ++j) {
                float4 ev = e4[j * 64 + lane];
                d += (double)xv[j].x * (double)ev.x + (double)xv[j].y * (double)ev.y
                   + (double)xv[j].z * (double)ev.z + (double)xv[j].w * (double)ev.w;
                ee += (double)ev.x * (double)ev.x + (double)ev.y * (double)ev.y
                    + (double)ev.z * (double)ev.z + (double)ev.w * (double)ev.w;
            }
            #pragma unroll
            for (int dd = 1; dd < 64; dd <<= 1) {
                d += __shfl_xor(d, dd);
                ee += __shfl_xor(ee, dd);
            }
            double sc = 2.0 * d - ee;
            if (sc > best_s || (sc == best_s && cidx < best_i)) { best_s = sc; best_i = cidx; }
        }
    }

    const float4* e4 = (const float4*)(E + (size_t)best_i * DIM);
    float4* o4 = (float4*)(outq + (size_t)token * DIM);
    float local = 0.0f;
    #pragma unroll
    for (int j = 0; j < 5; ++j) {
        float4 q = e4[j * 64 + lane];
        o4[j * 64 + lane] = q;
        float dx = xv[j].x - q.x, dy = xv[j].y - q.y;
        float dz = xv[j].z - q.z, dw = xv[j].w - q.w;
        local += dx * dx + dy * dy + dz * dz + dw * dw;
    }
    #pragma unroll
    for (int d = 1; d < 64; d <<= 1) local += __shfl_xor(local, d);
    if (lane == 0) {
        sums[token] = local;
        outidx[token] = (float)best_i;
    }
}

// ---------------------------------------------------------------------------
// Kernel 3: deterministic final loss reduction (fixed tree).
// ---------------------------------------------------------------------------
__global__ __launch_bounds__(256) void loss_kernel(
    const float* __restrict__ sums, float* __restrict__ out_loss)
{
    __shared__ double red[256];
    int t = threadIdx.x;
    double s = 0.0;
    for (int i = t; i < N_TOKENS; i += 256) s += (double)sums[i];
    red[t] = s;
    __syncthreads();
    for (int off = 128; off > 0; off >>= 1) {
        if (t < off) red[t] += red[t + off];
        __syncthreads();
    }
    if (t == 0) out_loss[0] = (float)(red[0] / (double)((size_t)N_TOKENS * DIM));
}

extern "C" void kernel_launch(void* const* d_in, const int* in_sizes, int n_in,
                              void* d_out, int out_size, void* d_ws, size_t ws_size,
                              hipStream_t stream)
{
    const float* X = (const float*)d_in[0];   // (32768, 1280) fp32
    const float* E = (const float*)d_in[1];   // (4096, 1280) fp32

    float* outq = (float*)d_out;                       // (32768,1280)
    float* outidx = outq + (size_t)N_TOKENS * DIM;     // (32768,) as float
    float* outloss = outidx + N_TOKENS;                // scalar

    // i8 temps + scales inside outq region (47.3 MB of 167.9 MB); consumed
    // by GEMM, then fully overwritten by refine_gather in-stream.
    signed char* Xq = (signed char*)d_out;                        // 41.9 MB
    signed char* Eq = Xq + (size_t)N_TOKENS * DIM;                // 5.2 MB
    float* sxs = (float*)(Eq + (size_t)N_CODES * DIM);            // 128 KB
    float* ses = sxs + N_TOKENS;                                  // 16 KB

    unsigned* pkeys = (unsigned*)d_ws;                            // 8 MB
    float* sums = (float*)((char*)d_ws + (size_t)N_TOKENS * 64 * sizeof(unsigned));

    quantize_i8_kernel<<<dim3((N_TOKENS + N_CODES) / 4), dim3(256), 0, stream>>>(
        X, E, Xq, Eq, sxs, ses);
    gemm_argmax_kernel<<<dim3(2048), dim3(1024), 0, stream>>>(Xq, Eq, sxs, ses, pkeys);
    refine_gather_kernel<<<dim3(N_TOKENS), dim3(64), 0, stream>>>(X, E, pkeys, outq, outidx, sums);
    loss_kernel<<<dim3(1), dim3(256), 0, stream>>>(sums, outloss);
}

// Round 12
// 373.332 us; speedup vs baseline: 1.0975x; 1.0496x over previous
//
#include <hip/hip_runtime.h>
#include <hip/hip_bf16.h>

typedef int i32x4 __attribute__((ext_vector_type(4)));

#define N_TOKENS 32768
#define N_CODES 4096
#define DIM 1280
#define NT 20            // K-tiles of 64 (i8)
#define BUFSZ 32768      // A 16KB + B 16KB per K-tile buffer

__device__ __forceinline__ void load_lds16(const void* g, void* l) {
    __builtin_amdgcn_global_load_lds(
        (const __attribute__((address_space(1))) unsigned int*)g,
        (__attribute__((address_space(3))) unsigned int*)l,
        16, 0, 0);
}

// ---------------------------------------------------------------------------
// Kernel 0: per-row symmetric int8 quantize (RNE), X and E fused in one
// launch (r11-verified). Exact-int dot => score err sigma ~3.4e-4, zero-mean;
// refine threshold 3e-3 ~ 9 sigma (r5-r11 verified).
// ---------------------------------------------------------------------------
__global__ __launch_bounds__(256) void quantize_i8_kernel(
    const float* __restrict__ X, const float* __restrict__ E,
    signed char* __restrict__ Xq, signed char* __restrict__ Eq,
    float* __restrict__ sxs, float* __restrict__ ses)
{
    int row = blockIdx.x * 4 + (threadIdx.x >> 6);
    const float* src;
    signed char* dst;
    float* scale;
    if (row < N_TOKENS) {
        src = X + (size_t)row * DIM; dst = Xq + (size_t)row * DIM; scale = sxs + row;
    } else {
        int r = row - N_TOKENS;
        if (r >= N_CODES) return;
        src = E + (size_t)r * DIM; dst = Eq + (size_t)r * DIM; scale = ses + r;
    }
    int lane = threadIdx.x & 63;
    const float4* s4 = (const float4*)src;
    float4 v[5];
    float amax = 0.f;
    #pragma unroll
    for (int j = 0; j < 5; ++j) {
        v[j] = s4[j * 64 + lane];
        amax = fmaxf(amax, fmaxf(fmaxf(fabsf(v[j].x), fabsf(v[j].y)),
                                 fmaxf(fabsf(v[j].z), fabsf(v[j].w))));
    }
    #pragma unroll
    for (int d = 1; d < 64; d <<= 1) amax = fmaxf(amax, __shfl_xor(amax, d));
    amax = fmaxf(amax, 1e-20f);
    float inv = 127.0f / amax;
    int* d4 = (int*)dst;
    #pragma unroll
    for (int j = 0; j < 5; ++j) {
        int q0 = (int)rintf(v[j].x * inv), q1 = (int)rintf(v[j].y * inv);
        int q2 = (int)rintf(v[j].z * inv), q3 = (int)rintf(v[j].w * inv);
        d4[j * 64 + lane] = (q0 & 0xFF) | ((q1 & 0xFF) << 8) |
                            ((q2 & 0xFF) << 16) | ((q3 & 0xFF) << 24);
    }
    if (lane == 0) *scale = amax * (1.0f / 127.0f);
}

// ---------------------------------------------------------------------------
// Kernel 1: i8 GEMM 256x256, 16 waves (4x4, wave tile 64x64), BK=64 —
// r6 CHAMPION SCHEDULE VERBATIM (the only structure that won across r6-r11:
// stage-issue BEFORE the MFMA burst, both operands on the depth-3 counted
// vmcnt ledger, 4 waves/SIMD at the 128-reg budget).
// Ledger (2 loads/thread/STAGE): prologue STAGE(0,1,2) [6 pending],
// vmcnt(4) retires S0 => tile 0 certified; barrier. Iter t: STAGE(t+3)
// [6 pending]; COMPUTE(t); vmcnt(4) retires S(t+1); barrier. Overwrite:
// STAGE(t+3) writes buf[(t+3)&3], last read iter t-1 pre-barrier => safe.
// Tail: COMPUTE(17) vmcnt(2); COMPUTE(18) vmcnt(0); COMPUTE(19).
// r11's cb0-ADJACENT XCD mapping grafted on (verified: FETCH 339->185 MB):
// xcd = bid&7, i = bid>>3; rb = i>>1, cb0 = 2*xcd + (i&1) — the two blocks
// sharing an A-panel (same rb) are launch-adjacent on the same XCD => the
// 327KB A-panel is read from HBM once, L2-served for the second block.
// ---------------------------------------------------------------------------
__global__ __launch_bounds__(1024, 4) void gemm_argmax_kernel(
    const signed char* __restrict__ Xq, const signed char* __restrict__ Eq,
    const float* __restrict__ sx, const float* __restrict__ se,
    unsigned* __restrict__ pkeys)
{
    __shared__ __align__(16) char lds[4 * BUFSZ];   // 128 KB

    int bid = blockIdx.x;
    int xcd = bid & 7, i = bid >> 3;          // i in 0..255 per XCD
    int cb0 = (xcd << 1) + (i & 1);           // adjacent pair shares rb
    int rb = i >> 1;                          // 0..127
    int row0 = rb << 8, col0 = cb0 << 8;

    int tid = threadIdx.x;
    int wid = tid >> 6, lane = tid & 63;
    int wm = wid >> 2, wn = wid & 3;          // 4x4 wave grid, tile 64x64
    int lr = lane & 15, g = lane >> 4;

    // per-lane swizzled fragment offsets (r6-verified; row bases multiples
    // of 16 => rp&7 == (lr>>1)&7)
    int slot = (((lr & 1) << 2) + g) ^ ((lr >> 1) & 7);
    int aoff = ((wm << 5) + (lr >> 1)) * 128 + slot * 16;            // A region
    int boff = 16384 + ((wn << 5) + (lr >> 1)) * 128 + slot * 16;    // B region

    i32x4 acc[4][4] = {};

    auto STAGE = [&](int t) {
        int base = (t & 3) * BUFSZ;
        int k0 = t << 6;                     // byte k-offset (i8)
        int f = tid;                         // slot 0..1023
        int rp = f >> 3, c = f & 7;
        int cp = c ^ (rp & 7);               // pre-swizzled source chunk
        int gr = (rp << 1) + (cp >> 2);      // global row in tile
        int kc = k0 + ((cp & 3) << 4);       // 16B k-chunk
        load_lds16(Xq + (size_t)(row0 + gr) * DIM + kc, lds + base + (f << 4));
        load_lds16(Eq + (size_t)(col0 + gr) * DIM + kc, lds + base + 16384 + (f << 4));
    };

    auto COMPUTE = [&](int t) {
        int base = (t & 3) * BUFSZ;
        const char* pA = lds + base + aoff;
        const char* pB = lds + base + boff;
        i32x4 a[4], b[4];
        #pragma unroll
        for (int m = 0; m < 4; ++m) a[m] = *(const i32x4*)(pA + (m << 10));
        #pragma unroll
        for (int n = 0; n < 4; ++n) b[n] = *(const i32x4*)(pB + (n << 10));
        __builtin_amdgcn_s_setprio(1);
        #pragma unroll
        for (int m = 0; m < 4; ++m)
            #pragma unroll
            for (int n = 0; n < 4; ++n)
                acc[m][n] = __builtin_amdgcn_mfma_i32_16x16x64_i8(
                    a[m], b[n], acc[m][n], 0, 0, 0);
        __builtin_amdgcn_s_setprio(0);
    };

    STAGE(0); STAGE(1); STAGE(2);                 // 6 outstanding
    asm volatile("s_waitcnt vmcnt(4)" ::: "memory");
    __builtin_amdgcn_s_barrier();
    __builtin_amdgcn_sched_barrier(0);

    #pragma unroll 1
    for (int t = 0; t < NT - 3; ++t) {
        STAGE(t + 3);
        COMPUTE(t);
        asm volatile("s_waitcnt vmcnt(4)" ::: "memory");
        __builtin_amdgcn_s_barrier();
        __builtin_amdgcn_sched_barrier(0);
    }
    COMPUTE(NT - 3);
    asm volatile("s_waitcnt vmcnt(2)" ::: "memory");
    __builtin_amdgcn_s_barrier();
    __builtin_amdgcn_sched_barrier(0);
    COMPUTE(NT - 2);
    asm volatile("s_waitcnt vmcnt(0)" ::: "memory");
    __builtin_amdgcn_s_barrier();
    __builtin_amdgcn_sched_barrier(0);
    COMPUTE(NT - 1);
    __syncthreads();   // drain; LDS reused for epilogue merge

    // ---- dequant + fused top-2 argmax epilogue (r6-verified) ----
    // C/D frag layout (dtype-independent): col = lr, row = g*4 + r.
    float se_l[4];
    #pragma unroll
    for (int n = 0; n < 4; ++n)
        se_l[n] = se[col0 + (wn << 6) + (n << 4) + lr];

    uint2* lk2 = (uint2*)lds;   // [256 rows][4 wn]
    #pragma unroll
    for (int m = 0; m < 4; ++m) {
        #pragma unroll
        for (int r = 0; r < 4; ++r) {
            int row = (wm << 6) + (m << 4) + (g << 2) + r;
            float fx = sx[row0 + row];
            unsigned b1 = 0, b2 = 0;
            #pragma unroll
            for (int n = 0; n < 4; ++n) {
                float s = (float)acc[m][n][r] * (fx * se_l[n]);
                int cib = ((wn & 1) << 6) + (n << 4) + lr;   // col in 128-block
                unsigned u = __float_as_uint(s);
                u = (u & 0x80000000u) ? ~u : (u | 0x80000000u);
                unsigned key = (u & 0xFFFFFF80u) | (unsigned)(127 - cib);
                if (key > b1) { b2 = b1; b1 = key; }
                else if (key > b2) b2 = key;
            }
            #pragma unroll
            for (int d = 1; d < 16; d <<= 1) {   // merge across 16 lanes (lr)
                unsigned o1 = __shfl_xor(b1, d), o2 = __shfl_xor(b2, d);
                if (o1 > b1) { b2 = (b1 > o2) ? b1 : o2; b1 = o1; }
                else if (o1 > b2) b2 = o1;
            }
            if (lr == 0) {
                uint2 v; v.x = b1; v.y = b2;
                lk2[(row << 2) + wn] = v;
            }
        }
    }
    __syncthreads();
    if (tid < 512) {
        // wn {0,1} -> 128-col-block h=0; wn {2,3} -> h=1
        int row = tid >> 1, h = tid & 1;
        uint2 p0 = lk2[(row << 2) + (h << 1)];
        uint2 p1 = lk2[(row << 2) + (h << 1) + 1];
        unsigned b1 = p0.x, b2 = p0.y;
        if (p1.x > b1) { b2 = (b1 > p1.y) ? b1 : p1.y; b1 = p1.x; }
        else if (p1.x > b2) b2 = p1.x;
        uint2 out; out.x = b1; out.y = b2;
        *(uint2*)&pkeys[((size_t)(row0 + row) << 6) + (((cb0 << 1) + h) << 1)] = out;
    }
}

// ---------------------------------------------------------------------------
// Kernel 2: fused exact fp64 refine + gather + loss partial. One wave/token.
// Threshold 3e-3 (~9 sigma i8 noise). FAST PATH (r11-verified): single
// candidate within threshold is provably the argmax -> skip fp64 rescore.
// ---------------------------------------------------------------------------
__global__ __launch_bounds__(64) void refine_gather_kernel(
    const float* __restrict__ X, const float* __restrict__ E,
    const unsigned* __restrict__ pkeys, float* __restrict__ outq,
    float* __restrict__ outidx, float* __restrict__ sums)
{
    int token = blockIdx.x;
    int lane = threadIdx.x;
    unsigned k = pkeys[((size_t)token << 6) + lane];
    unsigned m = k & 0xFFFFFF80u;
    float s = __uint_as_float((m & 0x80000000u) ? (m & 0x7FFFFFFFu) : ~m);
    float smax = s;
    #pragma unroll
    for (int d = 1; d < 64; d <<= 1) smax = fmaxf(smax, __shfl_xor(smax, d));
    bool cand = s >= smax - 3e-3f;
    unsigned long long ball = __ballot(cand);

    const float4* x4 = (const float4*)(X + (size_t)token * DIM);
    float4 xv[5];
    #pragma unroll
    for (int j = 0; j < 5; ++j) xv[j] = x4[j * 64 + lane];

    int best_i;
    if (__popcll(ball) == 1) {
        int src = __ffsll(ball) - 1;
        unsigned ck = __shfl(k, src);
        best_i = ((src >> 1) << 7) + (127 - (int)(ck & 127u));
    } else {
        double best_s = -1.0e300;
        best_i = 0x7FFFFFFF;
        while (ball) {
            int src = __ffsll(ball) - 1;
            ball &= ball - 1;
            unsigned ck = __shfl(k, src);
            int cidx = ((src >> 1) << 7) + (127 - (int)(ck & 127u));
            const float4* e4 = (const float4*)(E + (size_t)cidx * DIM);
            double d = 0.0, ee = 0.0;
            #pragma unroll
            for (int j = 0; j < 5; ++j) {
                float4 ev = e4[j * 64 + lane];
                d += (double)xv[j].x * (double)ev.x + (double)xv[j].y * (double)ev.y
                   + (double)xv[j].z * (double)ev.z + (double)xv[j].w * (double)ev.w;
                ee += (double)ev.x * (double)ev.x + (double)ev.y * (double)ev.y
                    + (double)ev.z * (double)ev.z + (double)ev.w * (double)ev.w;
            }
            #pragma unroll
            for (int dd = 1; dd < 64; dd <<= 1) {
                d += __shfl_xor(d, dd);
                ee += __shfl_xor(ee, dd);
            }
            double sc = 2.0 * d - ee;
            if (sc > best_s || (sc == best_s && cidx < best_i)) { best_s = sc; best_i = cidx; }
        }
    }

    const float4* e4 = (const float4*)(E + (size_t)best_i * DIM);
    float4* o4 = (float4*)(outq + (size_t)token * DIM);
    float local = 0.0f;
    #pragma unroll
    for (int j = 0; j < 5; ++j) {
        float4 q = e4[j * 64 + lane];
        o4[j * 64 + lane] = q;
        float dx = xv[j].x - q.x, dy = xv[j].y - q.y;
        float dz = xv[j].z - q.z, dw = xv[j].w - q.w;
        local += dx * dx + dy * dy + dz * dz + dw * dw;
    }
    #pragma unroll
    for (int d = 1; d < 64; d <<= 1) local += __shfl_xor(local, d);
    if (lane == 0) {
        sums[token] = local;
        outidx[token] = (float)best_i;
    }
}

// ---------------------------------------------------------------------------
// Kernel 3: deterministic final loss reduction (fixed tree).
// ---------------------------------------------------------------------------
__global__ __launch_bounds__(256) void loss_kernel(
    const float* __restrict__ sums, float* __restrict__ out_loss)
{
    __shared__ double red[256];
    int t = threadIdx.x;
    double s = 0.0;
    for (int i = t; i < N_TOKENS; i += 256) s += (double)sums[i];
    red[t] = s;
    __syncthreads();
    for (int off = 128; off > 0; off >>= 1) {
        if (t < off) red[t] += red[t + off];
        __syncthreads();
    }
    if (t == 0) out_loss[0] = (float)(red[0] / (double)((size_t)N_TOKENS * DIM));
}

extern "C" void kernel_launch(void* const* d_in, const int* in_sizes, int n_in,
                              void* d_out, int out_size, void* d_ws, size_t ws_size,
                              hipStream_t stream)
{
    const float* X = (const float*)d_in[0];   // (32768, 1280) fp32
    const float* E = (const float*)d_in[1];   // (4096, 1280) fp32

    float* outq = (float*)d_out;                       // (32768,1280)
    float* outidx = outq + (size_t)N_TOKENS * DIM;     // (32768,) as float
    float* outloss = outidx + N_TOKENS;                // scalar

    // i8 temps + scales inside outq region (47.3 MB of 167.9 MB); consumed
    // by GEMM, then fully overwritten by refine_gather in-stream.
    signed char* Xq = (signed char*)d_out;                        // 41.9 MB
    signed char* Eq = Xq + (size_t)N_TOKENS * DIM;                // 5.2 MB
    float* sxs = (float*)(Eq + (size_t)N_CODES * DIM);            // 128 KB
    float* ses = sxs + N_TOKENS;                                  // 16 KB

    unsigned* pkeys = (unsigned*)d_ws;                            // 8 MB
    float* sums = (float*)((char*)d_ws + (size_t)N_TOKENS * 64 * sizeof(unsigned));

    quantize_i8_kernel<<<dim3((N_TOKENS + N_CODES) / 4), dim3(256), 0, stream>>>(
        X, E, Xq, Eq, sxs, ses);
    gemm_argmax_kernel<<<dim3(2048), dim3(1024), 0, stream>>>(Xq, Eq, sxs, ses, pkeys);
    refine_gather_kernel<<<dim3(N_TOKENS), dim3(64), 0, stream>>>(X, E, pkeys, outq, outidx, sums);
    loss_kernel<<<dim3(1), dim3(256), 0, stream>>>(sums, outloss);
}

// Round 13
// 346.555 us; speedup vs baseline: 1.1823x; 1.0773x over previous
//
#include <hip/hip_runtime.h>
#include <hip/hip_bf16.h>

typedef int i32x4 __attribute__((ext_vector_type(4)));

#define N_TOKENS 32768
#define N_CODES 4096
#define DIM 1280
#define NT 20            // K-tiles of 64 (i8)
#define BUFSZ 32768      // A 16KB + B 16KB per K-tile buffer

__device__ __forceinline__ void load_lds16(const void* g, void* l) {
    __builtin_amdgcn_global_load_lds(
        (const __attribute__((address_space(1))) unsigned int*)g,
        (__attribute__((address_space(3))) unsigned int*)l,
        16, 0, 0);
}

// ---------------------------------------------------------------------------
// Kernel 0: per-row symmetric int8 quantize (RNE), X and E fused in one
// launch (r11-verified). Exact-int dot => score err sigma ~3.4e-4, zero-mean;
// refine threshold 3e-3 ~ 9 sigma (r5-r12 verified).
// ---------------------------------------------------------------------------
__global__ __launch_bounds__(256) void quantize_i8_kernel(
    const float* __restrict__ X, const float* __restrict__ E,
    signed char* __restrict__ Xq, signed char* __restrict__ Eq,
    float* __restrict__ sxs, float* __restrict__ ses)
{
    int row = blockIdx.x * 4 + (threadIdx.x >> 6);
    const float* src;
    signed char* dst;
    float* scale;
    if (row < N_TOKENS) {
        src = X + (size_t)row * DIM; dst = Xq + (size_t)row * DIM; scale = sxs + row;
    } else {
        int r = row - N_TOKENS;
        if (r >= N_CODES) return;
        src = E + (size_t)r * DIM; dst = Eq + (size_t)r * DIM; scale = ses + r;
    }
    int lane = threadIdx.x & 63;
    const float4* s4 = (const float4*)src;
    float4 v[5];
    float amax = 0.f;
    #pragma unroll
    for (int j = 0; j < 5; ++j) {
        v[j] = s4[j * 64 + lane];
        amax = fmaxf(amax, fmaxf(fmaxf(fabsf(v[j].x), fabsf(v[j].y)),
                                 fmaxf(fabsf(v[j].z), fabsf(v[j].w))));
    }
    #pragma unroll
    for (int d = 1; d < 64; d <<= 1) amax = fmaxf(amax, __shfl_xor(amax, d));
    amax = fmaxf(amax, 1e-20f);
    float inv = 127.0f / amax;
    int* d4 = (int*)dst;
    #pragma unroll
    for (int j = 0; j < 5; ++j) {
        int q0 = (int)rintf(v[j].x * inv), q1 = (int)rintf(v[j].y * inv);
        int q2 = (int)rintf(v[j].z * inv), q3 = (int)rintf(v[j].w * inv);
        d4[j * 64 + lane] = (q0 & 0xFF) | ((q1 & 0xFF) << 8) |
                            ((q2 & 0xFF) << 16) | ((q3 & 0xFF) << 24);
    }
    if (lane == 0) *scale = amax * (1.0f / 127.0f);
}

// ---------------------------------------------------------------------------
// Kernel 1: i8 GEMM 256x256, 16 waves (4x4, wave tile 64x64), BK=64 —
// r6 champion schedule + r11 cb0-adjacent XCD mapping. BYTE-IDENTICAL to the
// r12 kernel (232.7 us, MfmaUtil 34%, FETCH 185 MB).
// Ledger: prologue STAGE(0,1,2) [6 pending], vmcnt(4) certifies tile 0;
// iter t: STAGE(t+3); COMPUTE(t); vmcnt(4) certifies t+1; barrier. Overwrite
// distance: STAGE(t+3) -> buf[(t+3)&3], last read iter t-1 pre-barrier.
// Closed cycle model (r12): 3490 cyc/iter = 1536 LDS-read + 1306 MFMA +
// 512 stage-write + barrier, additive at 4 waves/SIMD / 128-reg budget.
// ---------------------------------------------------------------------------
__global__ __launch_bounds__(1024, 4) void gemm_argmax_kernel(
    const signed char* __restrict__ Xq, const signed char* __restrict__ Eq,
    const float* __restrict__ sx, const float* __restrict__ se,
    unsigned* __restrict__ pkeys)
{
    __shared__ __align__(16) char lds[4 * BUFSZ];   // 128 KB

    int bid = blockIdx.x;
    int xcd = bid & 7, i = bid >> 3;          // i in 0..255 per XCD
    int cb0 = (xcd << 1) + (i & 1);           // adjacent pair shares rb
    int rb = i >> 1;                          // 0..127
    int row0 = rb << 8, col0 = cb0 << 8;

    int tid = threadIdx.x;
    int wid = tid >> 6, lane = tid & 63;
    int wm = wid >> 2, wn = wid & 3;          // 4x4 wave grid, tile 64x64
    int lr = lane & 15, g = lane >> 4;

    int slot = (((lr & 1) << 2) + g) ^ ((lr >> 1) & 7);
    int aoff = ((wm << 5) + (lr >> 1)) * 128 + slot * 16;            // A region
    int boff = 16384 + ((wn << 5) + (lr >> 1)) * 128 + slot * 16;    // B region

    i32x4 acc[4][4] = {};

    auto STAGE = [&](int t) {
        int base = (t & 3) * BUFSZ;
        int k0 = t << 6;                     // byte k-offset (i8)
        int f = tid;                         // slot 0..1023
        int rp = f >> 3, c = f & 7;
        int cp = c ^ (rp & 7);               // pre-swizzled source chunk
        int gr = (rp << 1) + (cp >> 2);      // global row in tile
        int kc = k0 + ((cp & 3) << 4);       // 16B k-chunk
        load_lds16(Xq + (size_t)(row0 + gr) * DIM + kc, lds + base + (f << 4));
        load_lds16(Eq + (size_t)(col0 + gr) * DIM + kc, lds + base + 16384 + (f << 4));
    };

    auto COMPUTE = [&](int t) {
        int base = (t & 3) * BUFSZ;
        const char* pA = lds + base + aoff;
        const char* pB = lds + base + boff;
        i32x4 a[4], b[4];
        #pragma unroll
        for (int m = 0; m < 4; ++m) a[m] = *(const i32x4*)(pA + (m << 10));
        #pragma unroll
        for (int n = 0; n < 4; ++n) b[n] = *(const i32x4*)(pB + (n << 10));
        __builtin_amdgcn_s_setprio(1);
        #pragma unroll
        for (int m = 0; m < 4; ++m)
            #pragma unroll
            for (int n = 0; n < 4; ++n)
                acc[m][n] = __builtin_amdgcn_mfma_i32_16x16x64_i8(
                    a[m], b[n], acc[m][n], 0, 0, 0);
        __builtin_amdgcn_s_setprio(0);
    };

    STAGE(0); STAGE(1); STAGE(2);                 // 6 outstanding
    asm volatile("s_waitcnt vmcnt(4)" ::: "memory");
    __builtin_amdgcn_s_barrier();
    __builtin_amdgcn_sched_barrier(0);

    #pragma unroll 1
    for (int t = 0; t < NT - 3; ++t) {
        STAGE(t + 3);
        COMPUTE(t);
        asm volatile("s_waitcnt vmcnt(4)" ::: "memory");
        __builtin_amdgcn_s_barrier();
        __builtin_amdgcn_sched_barrier(0);
    }
    COMPUTE(NT - 3);
    asm volatile("s_waitcnt vmcnt(2)" ::: "memory");
    __builtin_amdgcn_s_barrier();
    __builtin_amdgcn_sched_barrier(0);
    COMPUTE(NT - 2);
    asm volatile("s_waitcnt vmcnt(0)" ::: "memory");
    __builtin_amdgcn_s_barrier();
    __builtin_amdgcn_sched_barrier(0);
    COMPUTE(NT - 1);
    __syncthreads();   // drain; LDS reused for epilogue merge

    // ---- dequant + fused top-2 argmax epilogue (r6-verified) ----
    float se_l[4];
    #pragma unroll
    for (int n = 0; n < 4; ++n)
        se_l[n] = se[col0 + (wn << 6) + (n << 4) + lr];

    uint2* lk2 = (uint2*)lds;   // [256 rows][4 wn]
    #pragma unroll
    for (int m = 0; m < 4; ++m) {
        #pragma unroll
        for (int r = 0; r < 4; ++r) {
            int row = (wm << 6) + (m << 4) + (g << 2) + r;
            float fx = sx[row0 + row];
            unsigned b1 = 0, b2 = 0;
            #pragma unroll
            for (int n = 0; n < 4; ++n) {
                float s = (float)acc[m][n][r] * (fx * se_l[n]);
                int cib = ((wn & 1) << 6) + (n << 4) + lr;   // col in 128-block
                unsigned u = __float_as_uint(s);
                u = (u & 0x80000000u) ? ~u : (u | 0x80000000u);
                unsigned key = (u & 0xFFFFFF80u) | (unsigned)(127 - cib);
                if (key > b1) { b2 = b1; b1 = key; }
                else if (key > b2) b2 = key;
            }
            #pragma unroll
            for (int d = 1; d < 16; d <<= 1) {
                unsigned o1 = __shfl_xor(b1, d), o2 = __shfl_xor(b2, d);
                if (o1 > b1) { b2 = (b1 > o2) ? b1 : o2; b1 = o1; }
                else if (o1 > b2) b2 = o1;
            }
            if (lr == 0) {
                uint2 v; v.x = b1; v.y = b2;
                lk2[(row << 2) + wn] = v;
            }
        }
    }
    __syncthreads();
    if (tid < 512) {
        int row = tid >> 1, h = tid & 1;
        uint2 p0 = lk2[(row << 2) + (h << 1)];
        uint2 p1 = lk2[(row << 2) + (h << 1) + 1];
        unsigned b1 = p0.x, b2 = p0.y;
        if (p1.x > b1) { b2 = (b1 > p1.y) ? b1 : p1.y; b1 = p1.x; }
        else if (p1.x > b2) b2 = p1.x;
        uint2 out; out.x = b1; out.y = b2;
        *(uint2*)&pkeys[((size_t)(row0 + row) << 6) + (((cb0 << 1) + h) << 1)] = out;
    }
}

// ---------------------------------------------------------------------------
// Kernel 2: fused exact fp64 refine + gather + loss partial. 4 TOKENS PER
// 256-THREAD BLOCK (one wave each) — 64-thr workgroups hit the per-CU
// workgroup-slot cap (~16 wg/CU = 50% occupancy) and under-saturated the
// HBM-write-bound stream. All logic is wave-local (__ballot/__shfl are
// per-wave), unchanged from the r11/r12-verified version.
// ---------------------------------------------------------------------------
__global__ __launch_bounds__(256) void refine_gather_kernel(
    const float* __restrict__ X, const float* __restrict__ E,
    const unsigned* __restrict__ pkeys, float* __restrict__ outq,
    float* __restrict__ outidx, float* __restrict__ sums)
{
    int token = blockIdx.x * 4 + (threadIdx.x >> 6);
    int lane = threadIdx.x & 63;
    unsigned k = pkeys[((size_t)token << 6) + lane];
    unsigned m = k & 0xFFFFFF80u;
    float s = __uint_as_float((m & 0x80000000u) ? (m & 0x7FFFFFFFu) : ~m);
    float smax = s;
    #pragma unroll
    for (int d = 1; d < 64; d <<= 1) smax = fmaxf(smax, __shfl_xor(smax, d));
    bool cand = s >= smax - 3e-3f;
    unsigned long long ball = __ballot(cand);

    const float4* x4 = (const float4*)(X + (size_t)token * DIM);
    float4 xv[5];
    #pragma unroll
    for (int j = 0; j < 5; ++j) xv[j] = x4[j * 64 + lane];

    int best_i;
    if (__popcll(ball) == 1) {
        int src = __ffsll(ball) - 1;
        unsigned ck = __shfl(k, src);
        best_i = ((src >> 1) << 7) + (127 - (int)(ck & 127u));
    } else {
        double best_s = -1.0e300;
        best_i = 0x7FFFFFFF;
        while (ball) {
            int src = __ffsll(ball) - 1;
            ball &= ball - 1;
            unsigned ck = __shfl(k, src);
            int cidx = ((src >> 1) << 7) + (127 - (int)(ck & 127u));
            const float4* e4 = (const float4*)(E + (size_t)cidx * DIM);
            double d = 0.0, ee = 0.0;
            #pragma unroll
            for (int j = 0; j < 5; ++j) {
                float4 ev = e4[j * 64 + lane];
                d += (double)xv[j].x * (double)ev.x + (double)xv[j].y * (double)ev.y
                   + (double)xv[j].z * (double)ev.z + (double)xv[j].w * (double)ev.w;
                ee += (double)ev.x * (double)ev.x + (double)ev.y * (double)ev.y
                    + (double)ev.z * (double)ev.z + (double)ev.w * (double)ev.w;
            }
            #pragma unroll
            for (int dd = 1; dd < 64; dd <<= 1) {
                d += __shfl_xor(d, dd);
                ee += __shfl_xor(ee, dd);
            }
            double sc = 2.0 * d - ee;
            if (sc > best_s || (sc == best_s && cidx < best_i)) { best_s = sc; best_i = cidx; }
        }
    }

    const float4* e4 = (const float4*)(E + (size_t)best_i * DIM);
    float4* o4 = (float4*)(outq + (size_t)token * DIM);
    float local = 0.0f;
    #pragma unroll
    for (int j = 0; j < 5; ++j) {
        float4 q = e4[j * 64 + lane];
        o4[j * 64 + lane] = q;
        float dx = xv[j].x - q.x, dy = xv[j].y - q.y;
        float dz = xv[j].z - q.z, dw = xv[j].w - q.w;
        local += dx * dx + dy * dy + dz * dz + dw * dw;
    }
    #pragma unroll
    for (int d = 1; d < 64; d <<= 1) local += __shfl_xor(local, d);
    if (lane == 0) {
        sums[token] = local;
        outidx[token] = (float)best_i;
    }
}

// ---------------------------------------------------------------------------
// Kernel 3a/3b: two-stage deterministic loss reduction (fixed assignment,
// fixed tree at both stages => bitwise deterministic). Stage 1: 128 blocks
// of 256 threads, each reduces a contiguous 256-value slice. Stage 2: one
// block reduces the 128 partials and finalizes.
// ---------------------------------------------------------------------------
__global__ __launch_bounds__(256) void loss_partial_kernel(
    const float* __restrict__ sums, double* __restrict__ partial)
{
    __shared__ double red[4];
    int t = threadIdx.x;
    double s = (double)sums[blockIdx.x * 256 + t];
    #pragma unroll
    for (int d = 1; d < 64; d <<= 1) s += __shfl_xor(s, d);
    if ((t & 63) == 0) red[t >> 6] = s;
    __syncthreads();
    if (t == 0) partial[blockIdx.x] = (red[0] + red[1]) + (red[2] + red[3]);
}

__global__ __launch_bounds__(128) void loss_final_kernel(
    const double* __restrict__ partial, float* __restrict__ out_loss)
{
    __shared__ double red[2];
    int t = threadIdx.x;
    double s = partial[t];
    #pragma unroll
    for (int d = 1; d < 64; d <<= 1) s += __shfl_xor(s, d);
    if ((t & 63) == 0) red[t >> 6] = s;
    __syncthreads();
    if (t == 0)
        out_loss[0] = (float)((red[0] + red[1]) / (double)((size_t)N_TOKENS * DIM));
}

extern "C" void kernel_launch(void* const* d_in, const int* in_sizes, int n_in,
                              void* d_out, int out_size, void* d_ws, size_t ws_size,
                              hipStream_t stream)
{
    const float* X = (const float*)d_in[0];   // (32768, 1280) fp32
    const float* E = (const float*)d_in[1];   // (4096, 1280) fp32

    float* outq = (float*)d_out;                       // (32768,1280)
    float* outidx = outq + (size_t)N_TOKENS * DIM;     // (32768,) as float
    float* outloss = outidx + N_TOKENS;                // scalar

    // i8 temps + scales inside outq region (47.3 MB of 167.9 MB); consumed
    // by GEMM, then fully overwritten by refine_gather in-stream.
    signed char* Xq = (signed char*)d_out;                        // 41.9 MB
    signed char* Eq = Xq + (size_t)N_TOKENS * DIM;                // 5.2 MB
    float* sxs = (float*)(Eq + (size_t)N_CODES * DIM);            // 128 KB
    float* ses = sxs + N_TOKENS;                                  // 16 KB

    unsigned* pkeys = (unsigned*)d_ws;                            // 8 MB
    float* sums = (float*)((char*)d_ws + (size_t)N_TOKENS * 64 * sizeof(unsigned));
    double* partial = (double*)(sums + N_TOKENS);                 // 1 KB

    quantize_i8_kernel<<<dim3((N_TOKENS + N_CODES) / 4), dim3(256), 0, stream>>>(
        X, E, Xq, Eq, sxs, ses);
    gemm_argmax_kernel<<<dim3(2048), dim3(1024), 0, stream>>>(Xq, Eq, sxs, ses, pkeys);
    refine_gather_kernel<<<dim3(N_TOKENS / 4), dim3(256), 0, stream>>>(
        X, E, pkeys, outq, outidx, sums);
    loss_partial_kernel<<<dim3(128), dim3(256), 0, stream>>>(sums, partial);
    loss_final_kernel<<<dim3(1), dim3(128), 0, stream>>>(partial, outloss);
}

// Round 14
// 345.285 us; speedup vs baseline: 1.1866x; 1.0037x over previous
//
#include <hip/hip_runtime.h>
#include <hip/hip_bf16.h>

typedef int i32x4 __attribute__((ext_vector_type(4)));

#define N_TOKENS 32768
#define N_CODES 4096
#define DIM 1280
#define NT 20            // K-tiles of 64 (i8)
#define BUFSZ 32768      // A 16KB + B 16KB per K-tile buffer

__device__ __forceinline__ void load_lds16(const void* g, void* l) {
    __builtin_amdgcn_global_load_lds(
        (const __attribute__((address_space(1))) unsigned int*)g,
        (__attribute__((address_space(3))) unsigned int*)l,
        16, 0, 0);
}

// ---------------------------------------------------------------------------
// Kernel 0: per-row symmetric int8 quantize (RNE), X and E fused (r11-r13
// verified). Exact-int dot => score err sigma ~3.4e-4; refine thr 3e-3.
// ---------------------------------------------------------------------------
__global__ __launch_bounds__(256) void quantize_i8_kernel(
    const float* __restrict__ X, const float* __restrict__ E,
    signed char* __restrict__ Xq, signed char* __restrict__ Eq,
    float* __restrict__ sxs, float* __restrict__ ses)
{
    int row = blockIdx.x * 4 + (threadIdx.x >> 6);
    const float* src;
    signed char* dst;
    float* scale;
    if (row < N_TOKENS) {
        src = X + (size_t)row * DIM; dst = Xq + (size_t)row * DIM; scale = sxs + row;
    } else {
        int r = row - N_TOKENS;
        if (r >= N_CODES) return;
        src = E + (size_t)r * DIM; dst = Eq + (size_t)r * DIM; scale = ses + r;
    }
    int lane = threadIdx.x & 63;
    const float4* s4 = (const float4*)src;
    float4 v[5];
    float amax = 0.f;
    #pragma unroll
    for (int j = 0; j < 5; ++j) {
        v[j] = s4[j * 64 + lane];
        amax = fmaxf(amax, fmaxf(fmaxf(fabsf(v[j].x), fabsf(v[j].y)),
                                 fmaxf(fabsf(v[j].z), fabsf(v[j].w))));
    }
    #pragma unroll
    for (int d = 1; d < 64; d <<= 1) amax = fmaxf(amax, __shfl_xor(amax, d));
    amax = fmaxf(amax, 1e-20f);
    float inv = 127.0f / amax;
    int* d4 = (int*)dst;
    #pragma unroll
    for (int j = 0; j < 5; ++j) {
        int q0 = (int)rintf(v[j].x * inv), q1 = (int)rintf(v[j].y * inv);
        int q2 = (int)rintf(v[j].z * inv), q3 = (int)rintf(v[j].w * inv);
        d4[j * 64 + lane] = (q0 & 0xFF) | ((q1 & 0xFF) << 8) |
                            ((q2 & 0xFF) << 16) | ((q3 & 0xFF) << 24);
    }
    if (lane == 0) *scale = amax * (1.0f / 127.0f);
}

// ---------------------------------------------------------------------------
// Kernel 1: i8 GEMM 256x256, 16 waves (4x4, 64x64 wave tile), BK=64 —
// r6/r12 champion + REGISTER FRAGMENT PREFETCH (tile t+1 ds_reads issued
// inside tile t's MFMA cluster -> MFMA(t) starts with zero lgkm wait; LDS
// and matrix pipes overlap instead of serializing).
//
// RE-DERIVED LEDGER (2 gl_lds/thread/STAGE, 4 buffers, depth-2):
//   prologue: STAGE(0,1,2) [6 pending]; vmcnt(2) retires S0,S1 => tiles 0,1
//             certified; barrier; LOADFRAG(0) (reads tile 0, certified).
//   iter t (entry invariant: pending = S(t+2); tiles t [in regs], t+1
//             certified in LDS):
//     STAGE(t+3)            [pending = S(t+2), S(t+3) = 4]
//     COMPUTE_PIPE(t):      16 MFMA on regs(t); interleaved 8 ds_read_b128
//                           prefetching frags(t+1) from buf[(t+1)&3]
//                           (certified at end of iter t-1; next write to
//                           that buffer is STAGE(t+5) at iter t+2).
//     vmcnt(2)              retires S(t+2) => tile t+2 certified
//     barrier; sched_barrier.
//   Overwrite: STAGE(t+3) -> buf[(t-1)&3]; its frags were prefetched at
//   iter t-2 and consumed by MFMA(t-1) (lgkm-ordered) before iter t-1's
//   end barrier => all reads complete before the write is issued.
//   Tail: loop t=0..16 (last STAGE(19) at t=16, end vmcnt(2) certifies 18);
//     t=17: COMPUTE_PIPE(17,pf); vmcnt(0) certifies 19; barrier;
//     t=18: COMPUTE_PIPE(18,pf);  t=19: COMPUTE_PIPE(19,nopf).
// Register cost: reload-in-place (a[m] refilled right after its 4 MFMAs);
// no second fragment set => stays in the 4-waves/SIMD budget.
// ---------------------------------------------------------------------------
__global__ __launch_bounds__(1024, 4) void gemm_argmax_kernel(
    const signed char* __restrict__ Xq, const signed char* __restrict__ Eq,
    const float* __restrict__ sx, const float* __restrict__ se,
    unsigned* __restrict__ pkeys)
{
    __shared__ __align__(16) char lds[4 * BUFSZ];   // 128 KB

    int bid = blockIdx.x;
    int xcd = bid & 7, i = bid >> 3;          // i in 0..255 per XCD
    int cb0 = (xcd << 1) + (i & 1);           // adjacent pair shares rb (r11)
    int rb = i >> 1;                          // 0..127
    int row0 = rb << 8, col0 = cb0 << 8;

    int tid = threadIdx.x;
    int wid = tid >> 6, lane = tid & 63;
    int wm = wid >> 2, wn = wid & 3;          // 4x4 wave grid, tile 64x64
    int lr = lane & 15, g = lane >> 4;

    int slot = (((lr & 1) << 2) + g) ^ ((lr >> 1) & 7);
    int aoff = ((wm << 5) + (lr >> 1)) * 128 + slot * 16;            // A region
    int boff = 16384 + ((wn << 5) + (lr >> 1)) * 128 + slot * 16;    // B region

    i32x4 acc[4][4] = {};
    i32x4 a[4], b[4];

    auto STAGE = [&](int t) {
        int base = (t & 3) * BUFSZ;
        int k0 = t << 6;                     // byte k-offset (i8)
        int f = tid;                         // slot 0..1023
        int rp = f >> 3, c = f & 7;
        int cp = c ^ (rp & 7);               // pre-swizzled source chunk
        int gr = (rp << 1) + (cp >> 2);      // global row in tile
        int kc = k0 + ((cp & 3) << 4);       // 16B k-chunk
        load_lds16(Xq + (size_t)(row0 + gr) * DIM + kc, lds + base + (f << 4));
        load_lds16(Eq + (size_t)(col0 + gr) * DIM + kc, lds + base + 16384 + (f << 4));
    };

    auto LOADFRAG = [&](int t) {
        int base = (t & 3) * BUFSZ;
        const char* pA = lds + base + aoff;
        const char* pB = lds + base + boff;
        #pragma unroll
        for (int m = 0; m < 4; ++m) a[m] = *(const i32x4*)(pA + (m << 10));
        #pragma unroll
        for (int n = 0; n < 4; ++n) b[n] = *(const i32x4*)(pB + (n << 10));
    };

    // MFMA on regs(t) with interleaved prefetch of frags(t+1)
    auto COMPUTE_PIPE = [&](int t, bool pf) {
        int nbase = ((t + 1) & 3) * BUFSZ;
        const char* pA1 = lds + nbase + aoff;
        const char* pB1 = lds + nbase + boff;
        __builtin_amdgcn_s_setprio(1);
        #pragma unroll
        for (int m = 0; m < 4; ++m) {
            #pragma unroll
            for (int n = 0; n < 4; ++n)
                acc[m][n] = __builtin_amdgcn_mfma_i32_16x16x64_i8(
                    a[m], b[n], acc[m][n], 0, 0, 0);
            if (pf) a[m] = *(const i32x4*)(pA1 + (m << 10));   // a[m] dead now
        }
        if (pf) {
            #pragma unroll
            for (int n = 0; n < 4; ++n) b[n] = *(const i32x4*)(pB1 + (n << 10));
        }
        __builtin_amdgcn_s_setprio(0);
    };

    STAGE(0); STAGE(1); STAGE(2);                 // 6 outstanding
    asm volatile("s_waitcnt vmcnt(2)" ::: "memory");   // certify tiles 0,1
    __builtin_amdgcn_s_barrier();
    __builtin_amdgcn_sched_barrier(0);
    LOADFRAG(0);

    #pragma unroll 1
    for (int t = 0; t < 17; ++t) {
        STAGE(t + 3);
        COMPUTE_PIPE(t, true);
        asm volatile("s_waitcnt vmcnt(2)" ::: "memory");   // certify t+2
        __builtin_amdgcn_s_barrier();
        __builtin_amdgcn_sched_barrier(0);
    }
    COMPUTE_PIPE(17, true);
    asm volatile("s_waitcnt vmcnt(0)" ::: "memory");       // certify 19
    __builtin_amdgcn_s_barrier();
    __builtin_amdgcn_sched_barrier(0);
    COMPUTE_PIPE(18, true);
    COMPUTE_PIPE(19, false);
    __syncthreads();   // drain; LDS reused for epilogue merge

    // ---- dequant + fused top-2 argmax epilogue (r6-r13 verified) ----
    float se_l[4];
    #pragma unroll
    for (int n = 0; n < 4; ++n)
        se_l[n] = se[col0 + (wn << 6) + (n << 4) + lr];

    uint2* lk2 = (uint2*)lds;   // [256 rows][4 wn]
    #pragma unroll
    for (int m = 0; m < 4; ++m) {
        #pragma unroll
        for (int r = 0; r < 4; ++r) {
            int row = (wm << 6) + (m << 4) + (g << 2) + r;
            float fx = sx[row0 + row];
            unsigned b1 = 0, b2 = 0;
            #pragma unroll
            for (int n = 0; n < 4; ++n) {
                float s = (float)acc[m][n][r] * (fx * se_l[n]);
                int cib = ((wn & 1) << 6) + (n << 4) + lr;   // col in 128-block
                unsigned u = __float_as_uint(s);
                u = (u & 0x80000000u) ? ~u : (u | 0x80000000u);
                unsigned key = (u & 0xFFFFFF80u) | (unsigned)(127 - cib);
                if (key > b1) { b2 = b1; b1 = key; }
                else if (key > b2) b2 = key;
            }
            #pragma unroll
            for (int d = 1; d < 16; d <<= 1) {
                unsigned o1 = __shfl_xor(b1, d), o2 = __shfl_xor(b2, d);
                if (o1 > b1) { b2 = (b1 > o2) ? b1 : o2; b1 = o1; }
                else if (o1 > b2) b2 = o1;
            }
            if (lr == 0) {
                uint2 v; v.x = b1; v.y = b2;
                lk2[(row << 2) + wn] = v;
            }
        }
    }
    __syncthreads();
    if (tid < 512) {
        int row = tid >> 1, h = tid & 1;
        uint2 p0 = lk2[(row << 2) + (h << 1)];
        uint2 p1 = lk2[(row << 2) + (h << 1) + 1];
        unsigned b1 = p0.x, b2 = p0.y;
        if (p1.x > b1) { b2 = (b1 > p1.y) ? b1 : p1.y; b1 = p1.x; }
        else if (p1.x > b2) b2 = p1.x;
        uint2 out; out.x = b1; out.y = b2;
        *(uint2*)&pkeys[((size_t)(row0 + row) << 6) + (((cb0 << 1) + h) << 1)] = out;
    }
}

// ---------------------------------------------------------------------------
// Kernel 2: fused exact fp64 refine + gather + loss partial. 4 tokens per
// 256-thread block (r13-verified occupancy fix); single-candidate fast path
// (r11-verified); threshold 3e-3.
// ---------------------------------------------------------------------------
__global__ __launch_bounds__(256) void refine_gather_kernel(
    const float* __restrict__ X, const float* __restrict__ E,
    const unsigned* __restrict__ pkeys, float* __restrict__ outq,
    float* __restrict__ outidx, float* __restrict__ sums)
{
    int token = blockIdx.x * 4 + (threadIdx.x >> 6);
    int lane = threadIdx.x & 63;
    unsigned k = pkeys[((size_t)token << 6) + lane];
    unsigned m = k & 0xFFFFFF80u;
    float s = __uint_as_float((m & 0x80000000u) ? (m & 0x7FFFFFFFu) : ~m);
    float smax = s;
    #pragma unroll
    for (int d = 1; d < 64; d <<= 1) smax = fmaxf(smax, __shfl_xor(smax, d));
    bool cand = s >= smax - 3e-3f;
    unsigned long long ball = __ballot(cand);

    const float4* x4 = (const float4*)(X + (size_t)token * DIM);
    float4 xv[5];
    #pragma unroll
    for (int j = 0; j < 5; ++j) xv[j] = x4[j * 64 + lane];

    int best_i;
    if (__popcll(ball) == 1) {
        int src = __ffsll(ball) - 1;
        unsigned ck = __shfl(k, src);
        best_i = ((src >> 1) << 7) + (127 - (int)(ck & 127u));
    } else {
        double best_s = -1.0e300;
        best_i = 0x7FFFFFFF;
        while (ball) {
            int src = __ffsll(ball) - 1;
            ball &= ball - 1;
            unsigned ck = __shfl(k, src);
            int cidx = ((src >> 1) << 7) + (127 - (int)(ck & 127u));
            const float4* e4 = (const float4*)(E + (size_t)cidx * DIM);
            double d = 0.0, ee = 0.0;
            #pragma unroll
            for (int j = 0; j < 5; ++j) {
                float4 ev = e4[j * 64 + lane];
                d += (double)xv[j].x * (double)ev.x + (double)xv[j].y * (double)ev.y
                   + (double)xv[j].z * (double)ev.z + (double)xv[j].w * (double)ev.w;
                ee += (double)ev.x * (double)ev.x + (double)ev.y * (double)ev.y
                    + (double)ev.z * (double)ev.z + (double)ev.w * (double)ev.w;
            }
            #pragma unroll
            for (int dd = 1; dd < 64; dd <<= 1) {
                d += __shfl_xor(d, dd);
                ee += __shfl_xor(ee, dd);
            }
            double sc = 2.0 * d - ee;
            if (sc > best_s || (sc == best_s && cidx < best_i)) { best_s = sc; best_i = cidx; }
        }
    }

    const float4* e4 = (const float4*)(E + (size_t)best_i * DIM);
    float4* o4 = (float4*)(outq + (size_t)token * DIM);
    float local = 0.0f;
    #pragma unroll
    for (int j = 0; j < 5; ++j) {
        float4 q = e4[j * 64 + lane];
        o4[j * 64 + lane] = q;
        float dx = xv[j].x - q.x, dy = xv[j].y - q.y;
        float dz = xv[j].z - q.z, dw = xv[j].w - q.w;
        local += dx * dx + dy * dy + dz * dz + dw * dw;
    }
    #pragma unroll
    for (int d = 1; d < 64; d <<= 1) local += __shfl_xor(local, d);
    if (lane == 0) {
        sums[token] = local;
        outidx[token] = (float)best_i;
    }
}

// ---------------------------------------------------------------------------
// Kernel 3a/3b: two-stage deterministic loss reduction (r13-verified).
// ---------------------------------------------------------------------------
__global__ __launch_bounds__(256) void loss_partial_kernel(
    const float* __restrict__ sums, double* __restrict__ partial)
{
    __shared__ double red[4];
    int t = threadIdx.x;
    double s = (double)sums[blockIdx.x * 256 + t];
    #pragma unroll
    for (int d = 1; d < 64; d <<= 1) s += __shfl_xor(s, d);
    if ((t & 63) == 0) red[t >> 6] = s;
    __syncthreads();
    if (t == 0) partial[blockIdx.x] = (red[0] + red[1]) + (red[2] + red[3]);
}

__global__ __launch_bounds__(128) void loss_final_kernel(
    const double* __restrict__ partial, float* __restrict__ out_loss)
{
    __shared__ double red[2];
    int t = threadIdx.x;
    double s = partial[t];
    #pragma unroll
    for (int d = 1; d < 64; d <<= 1) s += __shfl_xor(s, d);
    if ((t & 63) == 0) red[t >> 6] = s;
    __syncthreads();
    if (t == 0)
        out_loss[0] = (float)((red[0] + red[1]) / (double)((size_t)N_TOKENS * DIM));
}

extern "C" void kernel_launch(void* const* d_in, const int* in_sizes, int n_in,
                              void* d_out, int out_size, void* d_ws, size_t ws_size,
                              hipStream_t stream)
{
    const float* X = (const float*)d_in[0];   // (32768, 1280) fp32
    const float* E = (const float*)d_in[1];   // (4096, 1280) fp32

    float* outq = (float*)d_out;                       // (32768,1280)
    float* outidx = outq + (size_t)N_TOKENS * DIM;     // (32768,) as float
    float* outloss = outidx + N_TOKENS;                // scalar

    // i8 temps + scales inside outq region (47.3 MB of 167.9 MB); consumed
    // by GEMM, then fully overwritten by refine_gather in-stream.
    signed char* Xq = (signed char*)d_out;                        // 41.9 MB
    signed char* Eq = Xq + (size_t)N_TOKENS * DIM;                // 5.2 MB
    float* sxs = (float*)(Eq + (size_t)N_CODES * DIM);            // 128 KB
    float* ses = sxs + N_TOKENS;                                  // 16 KB

    unsigned* pkeys = (unsigned*)d_ws;                            // 8 MB
    float* sums = (float*)((char*)d_ws + (size_t)N_TOKENS * 64 * sizeof(unsigned));
    double* partial = (double*)(sums + N_TOKENS);                 // 1 KB

    quantize_i8_kernel<<<dim3((N_TOKENS + N_CODES) / 4), dim3(256), 0, stream>>>(
        X, E, Xq, Eq, sxs, ses);
    gemm_argmax_kernel<<<dim3(2048), dim3(1024), 0, stream>>>(Xq, Eq, sxs, ses, pkeys);
    refine_gather_kernel<<<dim3(N_TOKENS / 4), dim3(256), 0, stream>>>(
        X, E, pkeys, outq, outidx, sums);
    loss_partial_kernel<<<dim3(128), dim3(256), 0, stream>>>(sums, partial);
    loss_final_kernel<<<dim3(1), dim3(128), 0, stream>>>(partial, outloss);
}

// Round 15
// 341.600 us; speedup vs baseline: 1.1994x; 1.0108x over previous
//
#include <hip/hip_runtime.h>
#include <hip/hip_bf16.h>

typedef int i32x4 __attribute__((ext_vector_type(4)));

#define N_TOKENS 32768
#define N_CODES 4096
#define DIM 1280
#define NT 20            // K-tiles of 64 (i8)
#define BUFSZ 32768      // A 16KB + B 16KB per K-tile

__device__ __forceinline__ void load_lds16(const void* g, void* l) {
    __builtin_amdgcn_global_load_lds(
        (const __attribute__((address_space(1))) unsigned int*)g,
        (__attribute__((address_space(3))) unsigned int*)l,
        16, 0, 0);
}

// ---------------------------------------------------------------------------
// Kernel 0: per-row symmetric int8 quantize (RNE), X and E fused (r11-r14
// verified). Exact-int dot => score err sigma ~3.4e-4; refine thr 3e-3.
// ---------------------------------------------------------------------------
__global__ __launch_bounds__(256) void quantize_i8_kernel(
    const float* __restrict__ X, const float* __restrict__ E,
    signed char* __restrict__ Xq, signed char* __restrict__ Eq,
    float* __restrict__ sxs, float* __restrict__ ses)
{
    int row = blockIdx.x * 4 + (threadIdx.x >> 6);
    const float* src;
    signed char* dst;
    float* scale;
    if (row < N_TOKENS) {
        src = X + (size_t)row * DIM; dst = Xq + (size_t)row * DIM; scale = sxs + row;
    } else {
        int r = row - N_TOKENS;
        if (r >= N_CODES) return;
        src = E + (size_t)r * DIM; dst = Eq + (size_t)r * DIM; scale = ses + r;
    }
    int lane = threadIdx.x & 63;
    const float4* s4 = (const float4*)src;
    float4 v[5];
    float amax = 0.f;
    #pragma unroll
    for (int j = 0; j < 5; ++j) {
        v[j] = s4[j * 64 + lane];
        amax = fmaxf(amax, fmaxf(fmaxf(fabsf(v[j].x), fabsf(v[j].y)),
                                 fmaxf(fabsf(v[j].z), fabsf(v[j].w))));
    }
    #pragma unroll
    for (int d = 1; d < 64; d <<= 1) amax = fmaxf(amax, __shfl_xor(amax, d));
    amax = fmaxf(amax, 1e-20f);
    float inv = 127.0f / amax;
    int* d4 = (int*)dst;
    #pragma unroll
    for (int j = 0; j < 5; ++j) {
        int q0 = (int)rintf(v[j].x * inv), q1 = (int)rintf(v[j].y * inv);
        int q2 = (int)rintf(v[j].z * inv), q3 = (int)rintf(v[j].w * inv);
        d4[j * 64 + lane] = (q0 & 0xFF) | ((q1 & 0xFF) << 8) |
                            ((q2 & 0xFF) << 16) | ((q3 & 0xFF) << 24);
    }
    if (lane == 0) *scale = amax * (1.0f / 127.0f);
}

// ---------------------------------------------------------------------------
// Kernel 1: i8 GEMM 256x256, 16 waves (4x4, 64x64 wave tile), BK=64 —
// r6/r12 champion core with PAIR-SPAN scheduling: one barrier per 2 tiles.
//
// Buffers: 2 pair-buffers x 64KB (tiles {2s,2s+1} share pair-buf[s&1]).
// tile t base = ((t>>1)&1)*65536 + (t&1)*BUFSZ.
// SPAN LEDGER (2 gl_lds/thread/STAGE = 8 loads per pair):
//   prologue: STAGE(0),STAGE(1) -> pairbuf0 [8 pending]; vmcnt(0) (serial
//             HBM latency exposed ONCE, ~1us total); barrier.
//   span s (t=2s; entry invariant: pairbuf[s&1] certified, 0 pending):
//     STAGE(t+2),STAGE(t+3) -> pairbuf[(s+1)&1]   [8 pending]   (s<9)
//     COMPUTE(t); COMPUTE(t+1)  reads pairbuf[s&1]  (~5200 cyc)
//     vmcnt(0)   -- loads issued BEFORE the compute pair, ~5200 cyc ago
//                   >> 900-cyc HBM latency => drain is FREE (this is the
//                   r11 lesson inverted: r11 put vmcnt right after STAGE
//                   and ate the latency; here it's hidden under compute)
//     barrier; sched_barrier  -> all waves' loads done => pair certified.
//   Overwrite: STAGE at span s+1 writes pairbuf[s&1], whose frag reads were
//   consumed by MFMA before span s's end barrier => safe (r6 strength).
//   Final span (s=9): no stage, no vmcnt needed; __syncthreads() drains.
// Barrier count: 20 -> 10 (the ~900 cyc/iter overhead term halves in total).
// ---------------------------------------------------------------------------
__global__ __launch_bounds__(1024, 4) void gemm_argmax_kernel(
    const signed char* __restrict__ Xq, const signed char* __restrict__ Eq,
    const float* __restrict__ sx, const float* __restrict__ se,
    unsigned* __restrict__ pkeys)
{
    __shared__ __align__(16) char lds[4 * BUFSZ];   // 128 KB = 2 pair-buffers

    int bid = blockIdx.x;
    int xcd = bid & 7, i = bid >> 3;          // i in 0..255 per XCD
    int cb0 = (xcd << 1) + (i & 1);           // adjacent pair shares rb (r11)
    int rb = i >> 1;                          // 0..127
    int row0 = rb << 8, col0 = cb0 << 8;

    int tid = threadIdx.x;
    int wid = tid >> 6, lane = tid & 63;
    int wm = wid >> 2, wn = wid & 3;          // 4x4 wave grid, tile 64x64
    int lr = lane & 15, g = lane >> 4;

    int slot = (((lr & 1) << 2) + g) ^ ((lr >> 1) & 7);
    int aoff = ((wm << 5) + (lr >> 1)) * 128 + slot * 16;            // A region
    int boff = 16384 + ((wn << 5) + (lr >> 1)) * 128 + slot * 16;    // B region

    i32x4 acc[4][4] = {};

    auto TBASE = [&](int t) { return (((t >> 1) & 1) << 16) + ((t & 1) * BUFSZ); };

    auto STAGE = [&](int t) {
        int base = TBASE(t);
        int k0 = t << 6;                     // byte k-offset (i8)
        int f = tid;                         // slot 0..1023
        int rp = f >> 3, c = f & 7;
        int cp = c ^ (rp & 7);               // pre-swizzled source chunk
        int gr = (rp << 1) + (cp >> 2);      // global row in tile
        int kc = k0 + ((cp & 3) << 4);       // 16B k-chunk
        load_lds16(Xq + (size_t)(row0 + gr) * DIM + kc, lds + base + (f << 4));
        load_lds16(Eq + (size_t)(col0 + gr) * DIM + kc, lds + base + 16384 + (f << 4));
    };

    auto COMPUTE = [&](int t) {
        int base = TBASE(t);
        const char* pA = lds + base + aoff;
        const char* pB = lds + base + boff;
        i32x4 a[4], b[4];
        #pragma unroll
        for (int m = 0; m < 4; ++m) a[m] = *(const i32x4*)(pA + (m << 10));
        #pragma unroll
        for (int n = 0; n < 4; ++n) b[n] = *(const i32x4*)(pB + (n << 10));
        __builtin_amdgcn_s_setprio(1);
        #pragma unroll
        for (int m = 0; m < 4; ++m)
            #pragma unroll
            for (int n = 0; n < 4; ++n)
                acc[m][n] = __builtin_amdgcn_mfma_i32_16x16x64_i8(
                    a[m], b[n], acc[m][n], 0, 0, 0);
        __builtin_amdgcn_s_setprio(0);
    };

    STAGE(0); STAGE(1);                           // pairbuf0, 8 pending
    asm volatile("s_waitcnt vmcnt(0)" ::: "memory");
    __builtin_amdgcn_s_barrier();
    __builtin_amdgcn_sched_barrier(0);

    #pragma unroll 1
    for (int s = 0; s < 9; ++s) {
        int t = s * 2;
        STAGE(t + 2);
        STAGE(t + 3);
        COMPUTE(t);
        COMPUTE(t + 1);
        asm volatile("s_waitcnt vmcnt(0)" ::: "memory");   // hidden drain
        __builtin_amdgcn_s_barrier();
        __builtin_amdgcn_sched_barrier(0);
    }
    COMPUTE(18);
    COMPUTE(19);
    __syncthreads();   // drain; LDS reused for epilogue merge

    // ---- dequant + fused top-2 argmax epilogue (r6-r14 verified) ----
    float se_l[4];
    #pragma unroll
    for (int n = 0; n < 4; ++n)
        se_l[n] = se[col0 + (wn << 6) + (n << 4) + lr];

    uint2* lk2 = (uint2*)lds;   // [256 rows][4 wn]
    #pragma unroll
    for (int m = 0; m < 4; ++m) {
        #pragma unroll
        for (int r = 0; r < 4; ++r) {
            int row = (wm << 6) + (m << 4) + (g << 2) + r;
            float fx = sx[row0 + row];
            unsigned b1 = 0, b2 = 0;
            #pragma unroll
            for (int n = 0; n < 4; ++n) {
                float s = (float)acc[m][n][r] * (fx * se_l[n]);
                int cib = ((wn & 1) << 6) + (n << 4) + lr;   // col in 128-block
                unsigned u = __float_as_uint(s);
                u = (u & 0x80000000u) ? ~u : (u | 0x80000000u);
                unsigned key = (u & 0xFFFFFF80u) | (unsigned)(127 - cib);
                if (key > b1) { b2 = b1; b1 = key; }
                else if (key > b2) b2 = key;
            }
            #pragma unroll
            for (int d = 1; d < 16; d <<= 1) {
                unsigned o1 = __shfl_xor(b1, d), o2 = __shfl_xor(b2, d);
                if (o1 > b1) { b2 = (b1 > o2) ? b1 : o2; b1 = o1; }
                else if (o1 > b2) b2 = o1;
            }
            if (lr == 0) {
                uint2 v; v.x = b1; v.y = b2;
                lk2[(row << 2) + wn] = v;
            }
        }
    }
    __syncthreads();
    if (tid < 512) {
        int row = tid >> 1, h = tid & 1;
        uint2 p0 = lk2[(row << 2) + (h << 1)];
        uint2 p1 = lk2[(row << 2) + (h << 1) + 1];
        unsigned b1 = p0.x, b2 = p0.y;
        if (p1.x > b1) { b2 = (b1 > p1.y) ? b1 : p1.y; b1 = p1.x; }
        else if (p1.x > b2) b2 = p1.x;
        uint2 out; out.x = b1; out.y = b2;
        *(uint2*)&pkeys[((size_t)(row0 + row) << 6) + (((cb0 << 1) + h) << 1)] = out;
    }
}

// ---------------------------------------------------------------------------
// Kernel 2: fused exact fp64 refine + gather + loss partial. 4 tokens per
// 256-thread block (r13-verified); single-candidate fast path (r11-verified).
// ---------------------------------------------------------------------------
__global__ __launch_bounds__(256) void refine_gather_kernel(
    const float* __restrict__ X, const float* __restrict__ E,
    const unsigned* __restrict__ pkeys, float* __restrict__ outq,
    float* __restrict__ outidx, float* __restrict__ sums)
{
    int token = blockIdx.x * 4 + (threadIdx.x >> 6);
    int lane = threadIdx.x & 63;
    unsigned k = pkeys[((size_t)token << 6) + lane];
    unsigned m = k & 0xFFFFFF80u;
    float s = __uint_as_float((m & 0x80000000u) ? (m & 0x7FFFFFFFu) : ~m);
    float smax = s;
    #pragma unroll
    for (int d = 1; d < 64; d <<= 1) smax = fmaxf(smax, __shfl_xor(smax, d));
    bool cand = s >= smax - 3e-3f;
    unsigned long long ball = __ballot(cand);

    const float4* x4 = (const float4*)(X + (size_t)token * DIM);
    float4 xv[5];
    #pragma unroll
    for (int j = 0; j < 5; ++j) xv[j] = x4[j * 64 + lane];

    int best_i;
    if (__popcll(ball) == 1) {
        int src = __ffsll(ball) - 1;
        unsigned ck = __shfl(k, src);
        best_i = ((src >> 1) << 7) + (127 - (int)(ck & 127u));
    } else {
        double best_s = -1.0e300;
        best_i = 0x7FFFFFFF;
        while (ball) {
            int src = __ffsll(ball) - 1;
            ball &= ball - 1;
            unsigned ck = __shfl(k, src);
            int cidx = ((src >> 1) << 7) + (127 - (int)(ck & 127u));
            const float4* e4 = (const float4*)(E + (size_t)cidx * DIM);
            double d = 0.0, ee = 0.0;
            #pragma unroll
            for (int j = 0; j < 5; ++j) {
                float4 ev = e4[j * 64 + lane];
                d += (double)xv[j].x * (double)ev.x + (double)xv[j].y * (double)ev.y
                   + (double)xv[j].z * (double)ev.z + (double)xv[j].w * (double)ev.w;
                ee += (double)ev.x * (double)ev.x + (double)ev.y * (double)ev.y
                    + (double)ev.z * (double)ev.z + (double)ev.w * (double)ev.w;
            }
            #pragma unroll
            for (int dd = 1; dd < 64; dd <<= 1) {
                d += __shfl_xor(d, dd);
                ee += __shfl_xor(ee, dd);
            }
            double sc = 2.0 * d - ee;
            if (sc > best_s || (sc == best_s && cidx < best_i)) { best_s = sc; best_i = cidx; }
        }
    }

    const float4* e4 = (const float4*)(E + (size_t)best_i * DIM);
    float4* o4 = (float4*)(outq + (size_t)token * DIM);
    float local = 0.0f;
    #pragma unroll
    for (int j = 0; j < 5; ++j) {
        float4 q = e4[j * 64 + lane];
        o4[j * 64 + lane] = q;
        float dx = xv[j].x - q.x, dy = xv[j].y - q.y;
        float dz = xv[j].z - q.z, dw = xv[j].w - q.w;
        local += dx * dx + dy * dy + dz * dz + dw * dw;
    }
    #pragma unroll
    for (int d = 1; d < 64; d <<= 1) local += __shfl_xor(local, d);
    if (lane == 0) {
        sums[token] = local;
        outidx[token] = (float)best_i;
    }
}

// ---------------------------------------------------------------------------
// Kernel 3a/3b: two-stage deterministic loss reduction (r13-verified).
// ---------------------------------------------------------------------------
__global__ __launch_bounds__(256) void loss_partial_kernel(
    const float* __restrict__ sums, double* __restrict__ partial)
{
    __shared__ double red[4];
    int t = threadIdx.x;
    double s = (double)sums[blockIdx.x * 256 + t];
    #pragma unroll
    for (int d = 1; d < 64; d <<= 1) s += __shfl_xor(s, d);
    if ((t & 63) == 0) red[t >> 6] = s;
    __syncthreads();
    if (t == 0) partial[blockIdx.x] = (red[0] + red[1]) + (red[2] + red[3]);
}

__global__ __launch_bounds__(128) void loss_final_kernel(
    const double* __restrict__ partial, float* __restrict__ out_loss)
{
    __shared__ double red[2];
    int t = threadIdx.x;
    double s = partial[t];
    #pragma unroll
    for (int d = 1; d < 64; d <<= 1) s += __shfl_xor(s, d);
    if ((t & 63) == 0) red[t >> 6] = s;
    __syncthreads();
    if (t == 0)
        out_loss[0] = (float)((red[0] + red[1]) / (double)((size_t)N_TOKENS * DIM));
}

extern "C" void kernel_launch(void* const* d_in, const int* in_sizes, int n_in,
                              void* d_out, int out_size, void* d_ws, size_t ws_size,
                              hipStream_t stream)
{
    const float* X = (const float*)d_in[0];   // (32768, 1280) fp32
    const float* E = (const float*)d_in[1];   // (4096, 1280) fp32

    float* outq = (float*)d_out;                       // (32768,1280)
    float* outidx = outq + (size_t)N_TOKENS * DIM;     // (32768,) as float
    float* outloss = outidx + N_TOKENS;                // scalar

    // i8 temps + scales inside outq region (47.3 MB of 167.9 MB); consumed
    // by GEMM, then fully overwritten by refine_gather in-stream.
    signed char* Xq = (signed char*)d_out;                        // 41.9 MB
    signed char* Eq = Xq + (size_t)N_TOKENS * DIM;                // 5.2 MB
    float* sxs = (float*)(Eq + (size_t)N_CODES * DIM);            // 128 KB
    float* ses = sxs + N_TOKENS;                                  // 16 KB

    unsigned* pkeys = (unsigned*)d_ws;                            // 8 MB
    float* sums = (float*)((char*)d_ws + (size_t)N_TOKENS * 64 * sizeof(unsigned));
    double* partial = (double*)(sums + N_TOKENS);                 // 1 KB

    quantize_i8_kernel<<<dim3((N_TOKENS + N_CODES) / 4), dim3(256), 0, stream>>>(
        X, E, Xq, Eq, sxs, ses);
    gemm_argmax_kernel<<<dim3(2048), dim3(1024), 0, stream>>>(Xq, Eq, sxs, ses, pkeys);
    refine_gather_kernel<<<dim3(N_TOKENS / 4), dim3(256), 0, stream>>>(
        X, E, pkeys, outq, outidx, sums);
    loss_partial_kernel<<<dim3(128), dim3(256), 0, stream>>>(sums, partial);
    loss_final_kernel<<<dim3(1), dim3(128), 0, stream>>>(partial, outloss);
}